// Round 7
// baseline (21927.237 us; speedup 1.0000x reference)
//
#include <hip/hip_runtime.h>
#include <math.h>

#define B_    8
#define P_    8192
#define M_    2048
#define NNODE 16384      // B_*M_
#define NCOL  524288     // NNODE*32
#define EPS_  1e-5f

// ---- ws layout (bytes) ---- (identical to round 5/6, proven)
#define OFF_SX   0ull                        // 65536 f32 = 262144
#define OFF_KNN  (OFF_SX + 262144ull)        // 524288 i32 = 2097152
#define OFF_FT   (OFF_KNN + 2097152ull)      // 8*8192*64 f32 = 16777216
#define OFF_ST   (OFF_FT + 16777216ull)      // 768 f32 (pad 4096)
#define OFF_AF   (OFF_ST + 4096ull)          // 768 f32 (pad 4096)
#define OFF_W0   (OFF_AF + 4096ull)          // 67*64 f32 = 17152
#define OFF_W1   (OFF_W0 + 17152ull)         // 64*64 f32 = 16384
#define OFF_W2   (OFF_W1 + 16384ull)         // 64*128 f32 = 32768
#define OFF_Y1   (OFF_W2 + 32768ull)         // 524288*64 f32 = 134217728
// total ~147 MB

// ---------------- prep ----------------
__global__ __launch_bounds__(256) void k_prep(
    const float* __restrict__ xyz, const float* __restrict__ W0,
    const float* __restrict__ W1, const float* __restrict__ W2,
    float* __restrict__ sx, float* __restrict__ Wt0, float* __restrict__ Wt1,
    float* __restrict__ Wt2, float* __restrict__ stats, float* __restrict__ centers_out)
{
  int idx = blockIdx.x*256 + threadIdx.x;
  if (idx < B_*P_) {
    const float* p3 = xyz + (size_t)idx*3;
    float x = p3[0], y = p3[1], z = p3[2];
    sx[idx] = __fadd_rn(__fadd_rn(__fmul_rn(x,x), __fmul_rn(y,y)), __fmul_rn(z,z));
  }
  if (idx < NNODE*3) {
    int m2 = idx/3, comp = idx - m2*3;
    int b = m2 >> 11, m = m2 & 2047;
    int cp = (m * 8191) / 2047;   // exact floor == int32(linspace), verified
    centers_out[idx] = xyz[((size_t)(b*P_ + cp))*3 + comp];
  }
  if (idx < 67*64) { int c = idx >> 6, o = idx & 63;  Wt0[idx] = W0[o*67 + c]; }
  if (idx < 64*64) { int c = idx >> 6, o = idx & 63;  Wt1[idx] = W1[o*64 + c]; }
  if (idx < 64*128){ int c = idx >> 7, o = idx & 127; Wt2[idx] = W2[o*64 + c]; }
  if (idx < 768)   stats[idx] = 0.f;
}

// ---------------- feats (b,c,p) -> ft (b,p,c) ----------------
__global__ __launch_bounds__(256) void k_ft(const float* __restrict__ feats, float* __restrict__ ft)
{
  int blk = blockIdx.x;            // 8*128
  int b = blk >> 7; int pt = (blk & 127) * 64;
  __shared__ float tile[64][65];
  const float* fb = feats + (size_t)b*64*P_;
  int tid = threadIdx.x;
  #pragma unroll
  for (int i = 0; i < 16; ++i) {
    int idx = i*256 + tid; int c = idx >> 6, p = idx & 63;
    tile[c][p] = fb[(size_t)c*P_ + pt + p];
  }
  __syncthreads();
  float* fo = ft + ((size_t)b*P_ + pt)*64;
  #pragma unroll
  for (int i = 0; i < 16; ++i) {
    int idx = i*256 + tid; int p = idx >> 6, c = idx & 63;
    fo[(size_t)p*64 + c] = tile[c][p];
  }
}

// ---------------- KNN: VERIFIED BIT-MATCHED — DO NOT TOUCH ----------------
__global__ __launch_bounds__(256) void k_knn(const float* __restrict__ xyz,
                                             const float* __restrict__ sx,
                                             int* __restrict__ knn)
{
  const int tid = threadIdx.x;
  const int lane = tid & 63, wid = tid >> 6;
  __shared__ float wv[4]; __shared__ int wg[4];
  int c0 = blockIdx.x * 4;
  for (int cc = 0; cc < 4; ++cc) {
    int cid = c0 + cc;
    int b = cid >> 11, m = cid & 2047;
    int cp = (m * 8191) / 2047;
    const float* xb  = xyz + (size_t)b * P_ * 3;
    const float* sxb = sx + b * P_;
    float cx = xb[cp*3+0], cy = xb[cp*3+1], cz = xb[cp*3+2];
    float sc = sxb[cp];
    float fkey[32];
    #pragma unroll
    for (int i = 0; i < 32; ++i) {
      int p = i*256 + tid;
      float px = xb[p*3+0], py = xb[p*3+1], pz = xb[p*3+2];
      float dot = fmaf(cz, pz, fmaf(cy, py, __fmul_rn(cx, px)));
      fkey[i] = __fsub_rn(__fadd_rn(sc, sxb[p]), __fmul_rn(2.0f, dot));
    }
    unsigned rem = 0u;
    float bv = INFINITY; int bp = 0x7FFFFFFF;
    #pragma unroll
    for (int i = 0; i < 32; ++i)
      if (fkey[i] < bv) { bv = fkey[i]; bp = i*256 + tid; }
    for (int r = 0; r < 32; ++r) {
      float v = bv; int g = bp;
      #pragma unroll
      for (int off = 32; off > 0; off >>= 1) {
        float ov = __shfl_down(v, off, 64);
        int   og = __shfl_down(g, off, 64);
        if (ov < v || (ov == v && og < g)) { v = ov; g = og; }
      }
      __syncthreads();
      if (lane == 0) { wv[wid] = v; wg[wid] = g; }
      __syncthreads();
      v = wv[0]; g = wg[0];
      #pragma unroll
      for (int w = 1; w < 4; ++w) {
        float ov = wv[w]; int og = wg[w];
        if (ov < v || (ov == v && og < g)) { v = ov; g = og; }
      }
      if (tid == 0) knn[cid*32 + r] = g;
      if ((g & 255) == tid) {
        rem |= 1u << (g >> 8);
        bv = INFINITY; bp = 0x7FFFFFFF;
        #pragma unroll
        for (int i = 0; i < 32; ++i)
          if (!(rem & (1u<<i)) && fkey[i] < bv) { bv = fkey[i]; bp = i*256 + tid; }
      }
    }
  }
}

// ---------------- kA: gather + conv0 (LDS weights) -> stats0 ----------------
__global__ __launch_bounds__(256) void k_stat0(
    const float* __restrict__ xyz, const float* __restrict__ ft,
    const int* __restrict__ knn, const float* __restrict__ Wt0,
    const float* __restrict__ b0, float* __restrict__ stats0)
{
  __shared__ float WL[67*64];
  __shared__ float lsum[64], lsq[64];
  int tid = threadIdx.x, lane = tid & 63;
  for (int i = tid; i < 67*64; i += 256) WL[i] = Wt0[i];
  if (tid < 64) { lsum[tid] = 0.f; lsq[tid] = 0.f; }
  __syncthreads();
  int col = blockIdx.x*256 + tid;
  int node = col >> 5, b = node >> 11, p = knn[col];
  float acc[64];
  #pragma unroll
  for (int o = 0; o < 64; ++o) acc[o] = b0[o];
  const float* xp = xyz + ((size_t)(b*P_ + p))*3;
  float xs3[3] = {xp[0], xp[1], xp[2]};
  #pragma unroll
  for (int c = 0; c < 3; ++c)
    #pragma unroll
    for (int o = 0; o < 64; ++o) acc[o] = fmaf(WL[c*64+o], xs3[c], acc[o]);
  const float* fp = ft + ((size_t)(b*P_ + p))*64;
  #pragma unroll
  for (int c4 = 0; c4 < 64; c4 += 4) {
    float4 xv = *(const float4*)(fp + c4);
    float xs[4] = {xv.x, xv.y, xv.z, xv.w};
    #pragma unroll
    for (int u = 0; u < 4; ++u)
      #pragma unroll
      for (int o = 0; o < 64; ++o) acc[o] = fmaf(WL[(3+c4+u)*64+o], xs[u], acc[o]);
  }
  // rotated LDS-atomic stats: per instr 32 distinct banks, 2 lanes/bank (free)
  #pragma unroll
  for (int i = 0; i < 32; ++i) {
    int o = (i + lane) & 31;
    atomicAdd(&lsum[o], acc[o]);      atomicAdd(&lsq[o],  acc[o]*acc[o]);
    atomicAdd(&lsum[o+32], acc[o+32]); atomicAdd(&lsq[o+32], acc[o+32]*acc[o+32]);
  }
  __syncthreads();
  if (tid < 64) { atomicAdd(&stats0[tid], lsum[tid]); atomicAdd(&stats0[128+tid], lsq[tid]); }
}

// ---------------- kB: gather + conv0 -> bn0/relu -> conv1 -> y1 (no stats) ----------------
__global__ __launch_bounds__(256) void k_l01(
    const float* __restrict__ xyz, const float* __restrict__ ft,
    const int* __restrict__ knn, const float* __restrict__ Wt0,
    const float* __restrict__ b0, const float* __restrict__ aff0,
    const float* __restrict__ Wt1, const float* __restrict__ b1,
    float* __restrict__ y1)
{
  __shared__ float W0L[67*64];
  __shared__ float W1L[64*64];
  int tid = threadIdx.x;
  for (int i = tid; i < 67*64; i += 256) W0L[i] = Wt0[i];
  for (int i = tid; i < 64*64; i += 256) W1L[i] = Wt1[i];
  __syncthreads();
  int col = blockIdx.x*256 + tid;
  int node = col >> 5, b = node >> 11, p = knn[col];
  float x[64];
  #pragma unroll
  for (int o = 0; o < 64; ++o) x[o] = b0[o];
  const float* xp = xyz + ((size_t)(b*P_ + p))*3;
  float xs3[3] = {xp[0], xp[1], xp[2]};
  #pragma unroll
  for (int c = 0; c < 3; ++c)
    #pragma unroll
    for (int o = 0; o < 64; ++o) x[o] = fmaf(W0L[c*64+o], xs3[c], x[o]);
  const float* fp = ft + ((size_t)(b*P_ + p))*64;
  #pragma unroll
  for (int c4 = 0; c4 < 64; c4 += 4) {
    float4 xv = *(const float4*)(fp + c4);
    float xs[4] = {xv.x, xv.y, xv.z, xv.w};
    #pragma unroll
    for (int u = 0; u < 4; ++u)
      #pragma unroll
      for (int o = 0; o < 64; ++o) x[o] = fmaf(W0L[(3+c4+u)*64+o], xs[u], x[o]);
  }
  #pragma unroll
  for (int c = 0; c < 64; ++c)
    x[c] = fmaxf(fmaf(x[c], aff0[c], aff0[128+c]), 0.f);
  float* yrow = y1 + (size_t)col*64;
  #pragma unroll
  for (int ot = 0; ot < 2; ++ot) {
    float acc[32];
    #pragma unroll
    for (int o = 0; o < 32; ++o) acc[o] = b1[ot*32 + o];
    #pragma unroll
    for (int c = 0; c < 64; ++c)
      #pragma unroll
      for (int o = 0; o < 32; ++o) acc[o] = fmaf(W1L[c*64 + ot*32 + o], x[c], acc[o]);
    #pragma unroll
    for (int c4 = 0; c4 < 32; c4 += 4)
      *(float4*)(yrow + ot*32 + c4) = make_float4(acc[c4], acc[c4+1], acc[c4+2], acc[c4+3]);
  }
}

// ---------------- kC: stream stats over y1 [NCOL][64] ----------------
__global__ __launch_bounds__(256) void k_statY(const float* __restrict__ y,
                                               float* __restrict__ statsg)
{
  __shared__ float lsum[64], lsq[64];
  int tid = threadIdx.x, lane = tid & 63;
  if (tid < 64) { lsum[tid] = 0.f; lsq[tid] = 0.f; }
  __syncthreads();
  int c4 = (tid & 15) * 4;
  float s[4] = {0.f,0.f,0.f,0.f}, q[4] = {0.f,0.f,0.f,0.f};
  for (int row = blockIdx.x*16 + (tid >> 4); row < NCOL; row += gridDim.x*16) {
    float4 v = *(const float4*)(y + (size_t)row*64 + c4);
    s[0]+=v.x; q[0]+=v.x*v.x;
    s[1]+=v.y; q[1]+=v.y*v.y;
    s[2]+=v.z; q[2]+=v.z*v.z;
    s[3]+=v.w; q[3]+=v.w*v.w;
  }
  #pragma unroll
  for (int u = 0; u < 4; ++u) {
    s[u] += __shfl_xor(s[u], 16, 64); s[u] += __shfl_xor(s[u], 32, 64);
    q[u] += __shfl_xor(q[u], 16, 64); q[u] += __shfl_xor(q[u], 32, 64);
  }
  if (lane < 16) {
    #pragma unroll
    for (int u = 0; u < 4; ++u) { atomicAdd(&lsum[c4+u], s[u]); atomicAdd(&lsq[c4+u], q[u]); }
  }
  __syncthreads();
  if (tid < 64) { atomicAdd(&statsg[tid], lsum[tid]); atomicAdd(&statsg[128+tid], lsq[tid]); }
}

// ---------------- BN finalize ----------------
__global__ void k_fin(const float* __restrict__ stats, const float* __restrict__ g,
                      const float* __restrict__ be, float* __restrict__ aff, int C)
{
  int o = threadIdx.x;
  if (o < C) {
    float N = (float)NCOL;
    float mu = stats[o] / N;
    float var = stats[128+o]/N - mu*mu;
    float r = 1.0f / sqrtf(var + EPS_);
    float s = g[o]*r;
    aff[o] = s;
    aff[128+o] = fmaf(-mu, s, be[o]);
  }
}

// ---------------- kD: y1 -> bn1/relu -> conv2 (LDS W2) -> stats2 ----------------
__global__ __launch_bounds__(256) void k_stat2(
    const float* __restrict__ y1, const float* __restrict__ aff1,
    const float* __restrict__ Wt2, const float* __restrict__ b2,
    float* __restrict__ stats2)
{
  __shared__ float W2L[64*128];
  __shared__ float lsum[128], lsq[128];
  int tid = threadIdx.x, lane = tid & 63;
  for (int i = tid; i < 64*128; i += 256) W2L[i] = Wt2[i];
  if (tid < 128) { lsum[tid] = 0.f; lsq[tid] = 0.f; }
  __syncthreads();
  int col = blockIdx.x*256 + tid;
  const float* yrow = y1 + (size_t)col*64;
  float x[64];
  #pragma unroll
  for (int c4 = 0; c4 < 64; c4 += 4) {
    float4 v = *(const float4*)(yrow + c4);
    x[c4]   = fmaxf(fmaf(v.x, aff1[c4],   aff1[128+c4]),   0.f);
    x[c4+1] = fmaxf(fmaf(v.y, aff1[c4+1], aff1[128+c4+1]), 0.f);
    x[c4+2] = fmaxf(fmaf(v.z, aff1[c4+2], aff1[128+c4+2]), 0.f);
    x[c4+3] = fmaxf(fmaf(v.w, aff1[c4+3], aff1[128+c4+3]), 0.f);
  }
  #pragma unroll
  for (int ot = 0; ot < 4; ++ot) {
    float acc[32];
    #pragma unroll
    for (int o = 0; o < 32; ++o) acc[o] = b2[ot*32 + o];
    #pragma unroll
    for (int c = 0; c < 64; ++c)
      #pragma unroll
      for (int o = 0; o < 32; ++o) acc[o] = fmaf(W2L[c*128 + ot*32 + o], x[c], acc[o]);
    #pragma unroll
    for (int i = 0; i < 32; ++i) {
      int o = (i + lane) & 31;
      atomicAdd(&lsum[ot*32 + o], acc[o]);
      atomicAdd(&lsq[ot*32 + o],  acc[o]*acc[o]);
    }
  }
  __syncthreads();
  if (tid < 128) { atomicAdd(&stats2[tid], lsum[tid]); atomicAdd(&stats2[128+tid], lsq[tid]); }
}

// ---------------- kE: y1 -> bn1/relu -> conv2 -> bn2/relu -> max_k -> out ----------------
__global__ __launch_bounds__(256) void k_maxout(
    const float* __restrict__ y1, const float* __restrict__ aff1,
    const float* __restrict__ Wt2, const float* __restrict__ b2,
    const float* __restrict__ aff2, float* __restrict__ out)
{
  __shared__ float W2L[64*128];
  int tid = threadIdx.x;
  for (int i = tid; i < 64*128; i += 256) W2L[i] = Wt2[i];
  __syncthreads();
  int col = blockIdx.x*256 + tid;
  int j = col & 31;
  int node = col >> 5;
  const float* yrow = y1 + (size_t)col*64;
  float x[64];
  #pragma unroll
  for (int c4 = 0; c4 < 64; c4 += 4) {
    float4 v = *(const float4*)(yrow + c4);
    x[c4]   = fmaxf(fmaf(v.x, aff1[c4],   aff1[128+c4]),   0.f);
    x[c4+1] = fmaxf(fmaf(v.y, aff1[c4+1], aff1[128+c4+1]), 0.f);
    x[c4+2] = fmaxf(fmaf(v.z, aff1[c4+2], aff1[128+c4+2]), 0.f);
    x[c4+3] = fmaxf(fmaf(v.w, aff1[c4+3], aff1[128+c4+3]), 0.f);
  }
  int b = node >> 11, m = node & 2047;
  float* op = out + ((size_t)b*128)*2048 + m;
  #pragma unroll
  for (int ot = 0; ot < 4; ++ot) {
    float acc[32];
    #pragma unroll
    for (int o = 0; o < 32; ++o) acc[o] = b2[ot*32 + o];
    #pragma unroll
    for (int c = 0; c < 64; ++c)
      #pragma unroll
      for (int o = 0; o < 32; ++o) acc[o] = fmaf(W2L[c*128 + ot*32 + o], x[c], acc[o]);
    #pragma unroll
    for (int o = 0; o < 32; ++o) {
      int oo = ot*32 + o;
      float v = fmaxf(fmaf(acc[o], aff2[oo], aff2[128+oo]), 0.f);
      #pragma unroll
      for (int off = 1; off < 32; off <<= 1)
        v = fmaxf(v, __shfl_xor(v, off, 64));
      if (j == 0) op[(size_t)oo*2048] = v;
    }
  }
}

extern "C" void kernel_launch(void* const* d_in, const int* in_sizes, int n_in,
                              void* d_out, int out_size, void* d_ws, size_t ws_size,
                              hipStream_t stream)
{
  const float* xyz   = (const float*)d_in[0];
  const float* feats = (const float*)d_in[1];
  const float* W0 = (const float*)d_in[2];
  const float* b0 = (const float*)d_in[3];
  const float* g0 = (const float*)d_in[4];
  const float* be0= (const float*)d_in[5];
  const float* W1 = (const float*)d_in[6];
  const float* b1 = (const float*)d_in[7];
  const float* g1 = (const float*)d_in[8];
  const float* be1= (const float*)d_in[9];
  const float* W2 = (const float*)d_in[10];
  const float* b2 = (const float*)d_in[11];
  const float* g2 = (const float*)d_in[12];
  const float* be2= (const float*)d_in[13];

  char* ws = (char*)d_ws;
  float* sx    = (float*)(ws + OFF_SX);
  int*   knn   = (int*  )(ws + OFF_KNN);
  float* ft    = (float*)(ws + OFF_FT);
  float* stats = (float*)(ws + OFF_ST);
  float* aff   = (float*)(ws + OFF_AF);
  float* Wt0   = (float*)(ws + OFF_W0);
  float* Wt1   = (float*)(ws + OFF_W1);
  float* Wt2   = (float*)(ws + OFF_W2);
  float* y1    = (float*)(ws + OFF_Y1);

  float* centers_out = (float*)d_out;              // 8*2048*3
  float* feat_out    = (float*)d_out + NNODE*3;    // 8*128*2048

  k_prep<<<256, 256, 0, stream>>>(xyz, W0, W1, W2, sx, Wt0, Wt1, Wt2, stats, centers_out);
  k_ft  <<<1024, 256, 0, stream>>>(feats, ft);
  k_knn <<<NNODE/4, 256, 0, stream>>>(xyz, sx, knn);
  k_stat0<<<NCOL/256, 256, 0, stream>>>(xyz, ft, knn, Wt0, b0, stats + 0);
  k_fin  <<<1, 128, 0, stream>>>(stats + 0,   g0, be0, aff + 0,   64);
  k_l01  <<<NCOL/256, 256, 0, stream>>>(xyz, ft, knn, Wt0, b0, aff + 0, Wt1, b1, y1);
  k_statY<<<1024, 256, 0, stream>>>(y1, stats + 256);
  k_fin  <<<1, 128, 0, stream>>>(stats + 256, g1, be1, aff + 256, 64);
  k_stat2<<<NCOL/256, 256, 0, stream>>>(y1, aff + 256, Wt2, b2, stats + 512);
  k_fin  <<<1, 128, 0, stream>>>(stats + 512, g2, be2, aff + 512, 128);
  k_maxout<<<NCOL/256, 256, 0, stream>>>(y1, aff + 256, Wt2, b2, aff + 512, feat_out);
}

// Round 8
// 2897.707 us; speedup vs baseline: 7.5671x; 7.5671x over previous
//
#include <hip/hip_runtime.h>
#include <math.h>

#define B_    8
#define P_    8192
#define M_    2048
#define NNODE 16384      // B_*M_
#define NCOL  524288     // NNODE*32
#define EPS_  1e-5f

// ---- ws layout (bytes) ---- (proven ≤ budget since r5)
#define OFF_SX   0ull                        // 65536 f32 = 262144
#define OFF_KNN  (OFF_SX + 262144ull)        // 524288 i32 = 2097152
#define OFF_FT   (OFF_KNN + 2097152ull)      // 8*8192*64 f32 = 16777216
#define OFF_ST   (OFF_FT + 16777216ull)      // 768 f32 (pad 4096)
#define OFF_AF   (OFF_ST + 4096ull)          // 768 f32 (pad 4096)
#define OFF_W0   (OFF_AF + 4096ull)          // 67*64 f32 = 17152
#define OFF_W1   (OFF_W0 + 17152ull)         // 64*64 f32 = 16384
#define OFF_W2   (OFF_W1 + 16384ull)         // 64*128 f32 = 32768
#define OFF_Y1   (OFF_W2 + 32768ull)         // 524288*64 f32 = 134217728
// total ~153 MB

// ---------------- prep ----------------
__global__ __launch_bounds__(256) void k_prep(
    const float* __restrict__ xyz, const float* __restrict__ W0,
    const float* __restrict__ W1, const float* __restrict__ W2,
    float* __restrict__ sx, float* __restrict__ Wt0, float* __restrict__ Wt1,
    float* __restrict__ Wt2, float* __restrict__ stats, float* __restrict__ centers_out)
{
  int idx = blockIdx.x*256 + threadIdx.x;
  if (idx < B_*P_) {
    const float* p3 = xyz + (size_t)idx*3;
    float x = p3[0], y = p3[1], z = p3[2];
    sx[idx] = __fadd_rn(__fadd_rn(__fmul_rn(x,x), __fmul_rn(y,y)), __fmul_rn(z,z));
  }
  if (idx < NNODE*3) {
    int m2 = idx/3, comp = idx - m2*3;
    int b = m2 >> 11, m = m2 & 2047;
    int cp = (m * 8191) / 2047;   // exact floor == int32(linspace), verified
    centers_out[idx] = xyz[((size_t)(b*P_ + cp))*3 + comp];
  }
  if (idx < 67*64) { int c = idx >> 6, o = idx & 63;  Wt0[idx] = W0[o*67 + c]; }
  if (idx < 64*64) { int c = idx >> 6, o = idx & 63;  Wt1[idx] = W1[o*64 + c]; }
  if (idx < 64*128){ int c = idx >> 7, o = idx & 127; Wt2[idx] = W2[o*64 + c]; }
  if (idx < 768)   stats[idx] = 0.f;
}

// ---------------- feats (b,c,p) -> ft (b,p,c) ----------------
__global__ __launch_bounds__(256) void k_ft(const float* __restrict__ feats, float* __restrict__ ft)
{
  int blk = blockIdx.x;            // 8*128
  int b = blk >> 7; int pt = (blk & 127) * 64;
  __shared__ float tile[64][65];
  const float* fb = feats + (size_t)b*64*P_;
  int tid = threadIdx.x;
  #pragma unroll
  for (int i = 0; i < 16; ++i) {
    int idx = i*256 + tid; int c = idx >> 6, p = idx & 63;
    tile[c][p] = fb[(size_t)c*P_ + pt + p];
  }
  __syncthreads();
  float* fo = ft + ((size_t)b*P_ + pt)*64;
  #pragma unroll
  for (int i = 0; i < 16; ++i) {
    int idx = i*256 + tid; int p = idx >> 6, c = idx & 63;
    fo[(size_t)p*64 + c] = tile[c][p];
  }
}

// ---------------- KNN: VERIFIED BIT-MATCHED — DO NOT TOUCH ----------------
__global__ __launch_bounds__(256) void k_knn(const float* __restrict__ xyz,
                                             const float* __restrict__ sx,
                                             int* __restrict__ knn)
{
  const int tid = threadIdx.x;
  const int lane = tid & 63, wid = tid >> 6;
  __shared__ float wv[4]; __shared__ int wg[4];
  int c0 = blockIdx.x * 4;
  for (int cc = 0; cc < 4; ++cc) {
    int cid = c0 + cc;
    int b = cid >> 11, m = cid & 2047;
    int cp = (m * 8191) / 2047;
    const float* xb  = xyz + (size_t)b * P_ * 3;
    const float* sxb = sx + b * P_;
    float cx = xb[cp*3+0], cy = xb[cp*3+1], cz = xb[cp*3+2];
    float sc = sxb[cp];
    float fkey[32];
    #pragma unroll
    for (int i = 0; i < 32; ++i) {
      int p = i*256 + tid;
      float px = xb[p*3+0], py = xb[p*3+1], pz = xb[p*3+2];
      float dot = fmaf(cz, pz, fmaf(cy, py, __fmul_rn(cx, px)));
      fkey[i] = __fsub_rn(__fadd_rn(sc, sxb[p]), __fmul_rn(2.0f, dot));
    }
    unsigned rem = 0u;
    float bv = INFINITY; int bp = 0x7FFFFFFF;
    #pragma unroll
    for (int i = 0; i < 32; ++i)
      if (fkey[i] < bv) { bv = fkey[i]; bp = i*256 + tid; }
    for (int r = 0; r < 32; ++r) {
      float v = bv; int g = bp;
      #pragma unroll
      for (int off = 32; off > 0; off >>= 1) {
        float ov = __shfl_down(v, off, 64);
        int   og = __shfl_down(g, off, 64);
        if (ov < v || (ov == v && og < g)) { v = ov; g = og; }
      }
      __syncthreads();
      if (lane == 0) { wv[wid] = v; wg[wid] = g; }
      __syncthreads();
      v = wv[0]; g = wg[0];
      #pragma unroll
      for (int w = 1; w < 4; ++w) {
        float ov = wv[w]; int og = wg[w];
        if (ov < v || (ov == v && og < g)) { v = ov; g = og; }
      }
      if (tid == 0) knn[cid*32 + r] = g;
      if ((g & 255) == tid) {
        rem |= 1u << (g >> 8);
        bv = INFINITY; bp = 0x7FFFFFFF;
        #pragma unroll
        for (int i = 0; i < 32; ++i)
          if (!(rem & (1u<<i)) && fkey[i] < bv) { bv = fkey[i]; bp = i*256 + tid; }
      }
    }
  }
}

// ========== k_g0: conv0 GEMM + stats0 (no store). 4 iters x 128 cols ==========
__global__ __launch_bounds__(256) void k_g0(
    const float* __restrict__ xyz, const float* __restrict__ ft,
    const int* __restrict__ knn, const float* __restrict__ Wt0,
    const float* __restrict__ b0, float* __restrict__ stats0)
{
  __shared__ float X0T[67*130];          // [c][col], stride 130
  __shared__ float W0L[67*64];           // [c][o]
  const int tid = threadIdx.x, lane = tid & 63;
  for (int i = tid; i < 67*64; i += 256) W0L[i] = Wt0[i];
  const float4* W0L4 = (const float4*)W0L;

  const int col0 = 2*(lane & 31) + 64*(lane >> 5);  // 128 cols
  const int ob   = (tid >> 6) * 16;                  // 4 waves x 16 outs
  float ts[16], tq[16];
  #pragma unroll
  for (int i = 0; i < 16; ++i) { ts[i] = 0.f; tq[i] = 0.f; }

  for (int it = 0; it < 4; ++it) {
    int gcol = blockIdx.x*512 + it*128;
    int b = gcol >> 16;
    __syncthreads();                      // protect X0T from prev iter readers
    {   // stage: col = tid&127, half = tid>>7
      int scol = tid & 127, half = tid >> 7;
      int p = knn[gcol + scol];
      if (half == 0) {
        const float* xp = xyz + ((size_t)(b*P_ + p))*3;
        X0T[0*130 + scol] = xp[0];
        X0T[1*130 + scol] = xp[1];
        X0T[2*130 + scol] = xp[2];
      }
      const float4* fp4 = (const float4*)(ft + ((size_t)(b*P_ + p))*64 + half*32);
      #pragma unroll
      for (int j4 = 0; j4 < 8; ++j4) {
        float4 v = fp4[j4];
        int r = 3 + half*32 + j4*4;
        X0T[(r+0)*130 + scol] = v.x;
        X0T[(r+1)*130 + scol] = v.y;
        X0T[(r+2)*130 + scol] = v.z;
        X0T[(r+3)*130 + scol] = v.w;
      }
    }
    __syncthreads();
    float acc0[16], acc1[16];
    #pragma unroll
    for (int i = 0; i < 16; ++i) { acc0[i] = b0[ob+i]; acc1[i] = acc0[i]; }
    for (int c = 0; c < 67; ++c) {
      float x0 = X0T[c*130 + col0];
      float x1 = X0T[c*130 + col0 + 1];
      #pragma unroll
      for (int i4 = 0; i4 < 4; ++i4) {
        float4 w = W0L4[c*16 + (ob>>2) + i4];
        acc0[i4*4+0] = fmaf(w.x, x0, acc0[i4*4+0]); acc1[i4*4+0] = fmaf(w.x, x1, acc1[i4*4+0]);
        acc0[i4*4+1] = fmaf(w.y, x0, acc0[i4*4+1]); acc1[i4*4+1] = fmaf(w.y, x1, acc1[i4*4+1]);
        acc0[i4*4+2] = fmaf(w.z, x0, acc0[i4*4+2]); acc1[i4*4+2] = fmaf(w.z, x1, acc1[i4*4+2]);
        acc0[i4*4+3] = fmaf(w.w, x0, acc0[i4*4+3]); acc1[i4*4+3] = fmaf(w.w, x1, acc1[i4*4+3]);
      }
    }
    #pragma unroll
    for (int i = 0; i < 16; ++i) {
      ts[i] += acc0[i] + acc1[i];
      tq[i] += acc0[i]*acc0[i] + acc1[i]*acc1[i];
    }
  }
  // butterfly over full wave (all 64 lanes share ob)
  #pragma unroll
  for (int i = 0; i < 16; ++i) {
    float s = ts[i], q = tq[i];
    #pragma unroll
    for (int off = 1; off < 64; off <<= 1) {
      s += __shfl_xor(s, off, 64);
      q += __shfl_xor(q, off, 64);
    }
    if (lane == 0) { atomicAdd(&stats0[ob+i], s); atomicAdd(&stats0[128+ob+i], q); }
  }
}

// ========== k_g01: conv0 -> bn0/relu -> conv1 -> y1 + stats1. 8 iters x 64 cols ==========
__global__ __launch_bounds__(256) void k_g01(
    const float* __restrict__ xyz, const float* __restrict__ ft,
    const int* __restrict__ knn, const float* __restrict__ Wt0,
    const float* __restrict__ b0, const float* __restrict__ aff0,
    const float* __restrict__ Wt1, const float* __restrict__ b1,
    float* __restrict__ y1, float* __restrict__ stats1)
{
  __shared__ float S[67*66];             // X0T [67][66] then XT [64][66]
  __shared__ float W0L[67*64];
  __shared__ float W1L[64*64];
  const int tid = threadIdx.x, lane = tid & 63;
  for (int i = tid; i < 67*64; i += 256) W0L[i] = Wt0[i];
  for (int i = tid; i < 64*64; i += 256) W1L[i] = Wt1[i];
  const float4* W0L4 = (const float4*)W0L;
  const float4* W1L4 = (const float4*)W1L;

  const int col0 = 2*(lane & 31);        // 64 cols
  const int og   = tid >> 5;             // 8 out-groups x 8
  const int ob   = og * 8;
  float ts[8], tq[8];
  #pragma unroll
  for (int i = 0; i < 8; ++i) { ts[i] = 0.f; tq[i] = 0.f; }

  for (int it = 0; it < 8; ++it) {
    int gcol = blockIdx.x*512 + it*64;
    int b = gcol >> 16;
    __syncthreads();
    {   // stage gather: col = tid&63, q = tid>>6
      int scol = tid & 63, q = tid >> 6;
      int p = knn[gcol + scol];
      if (q == 0) {
        const float* xp = xyz + ((size_t)(b*P_ + p))*3;
        S[0*66 + scol] = xp[0];
        S[1*66 + scol] = xp[1];
        S[2*66 + scol] = xp[2];
      }
      const float4* fp4 = (const float4*)(ft + ((size_t)(b*P_ + p))*64 + q*16);
      #pragma unroll
      for (int j4 = 0; j4 < 4; ++j4) {
        float4 v = fp4[j4];
        int r = 3 + q*16 + j4*4;
        S[(r+0)*66 + scol] = v.x;
        S[(r+1)*66 + scol] = v.y;
        S[(r+2)*66 + scol] = v.z;
        S[(r+3)*66 + scol] = v.w;
      }
    }
    __syncthreads();
    // conv0 GEMM
    float acc0[8], acc1[8];
    #pragma unroll
    for (int i = 0; i < 8; ++i) { acc0[i] = b0[ob+i]; acc1[i] = acc0[i]; }
    for (int c = 0; c < 67; ++c) {
      float x0 = S[c*66 + col0];
      float x1 = S[c*66 + col0 + 1];
      #pragma unroll
      for (int i4 = 0; i4 < 2; ++i4) {
        float4 w = W0L4[c*16 + og*2 + i4];
        acc0[i4*4+0] = fmaf(w.x, x0, acc0[i4*4+0]); acc1[i4*4+0] = fmaf(w.x, x1, acc1[i4*4+0]);
        acc0[i4*4+1] = fmaf(w.y, x0, acc0[i4*4+1]); acc1[i4*4+1] = fmaf(w.y, x1, acc1[i4*4+1]);
        acc0[i4*4+2] = fmaf(w.z, x0, acc0[i4*4+2]); acc1[i4*4+2] = fmaf(w.z, x1, acc1[i4*4+2]);
        acc0[i4*4+3] = fmaf(w.w, x0, acc0[i4*4+3]); acc1[i4*4+3] = fmaf(w.w, x1, acc1[i4*4+3]);
      }
    }
    // bn0 + relu
    #pragma unroll
    for (int i = 0; i < 8; ++i) {
      int o = ob + i;
      acc0[i] = fmaxf(fmaf(acc0[i], aff0[o], aff0[128+o]), 0.f);
      acc1[i] = fmaxf(fmaf(acc1[i], aff0[o], aff0[128+o]), 0.f);
    }
    __syncthreads();                     // all X0T reads done before overwrite
    #pragma unroll
    for (int i = 0; i < 8; ++i) {
      S[(ob+i)*66 + col0]     = acc0[i];
      S[(ob+i)*66 + col0 + 1] = acc1[i];
    }
    __syncthreads();
    // conv1 GEMM
    float d0[8], d1[8];
    #pragma unroll
    for (int i = 0; i < 8; ++i) { d0[i] = b1[ob+i]; d1[i] = d0[i]; }
    for (int c = 0; c < 64; ++c) {
      float x0 = S[c*66 + col0];
      float x1 = S[c*66 + col0 + 1];
      #pragma unroll
      for (int i4 = 0; i4 < 2; ++i4) {
        float4 w = W1L4[c*16 + og*2 + i4];
        d0[i4*4+0] = fmaf(w.x, x0, d0[i4*4+0]); d1[i4*4+0] = fmaf(w.x, x1, d1[i4*4+0]);
        d0[i4*4+1] = fmaf(w.y, x0, d0[i4*4+1]); d1[i4*4+1] = fmaf(w.y, x1, d1[i4*4+1]);
        d0[i4*4+2] = fmaf(w.z, x0, d0[i4*4+2]); d1[i4*4+2] = fmaf(w.z, x1, d1[i4*4+2]);
        d0[i4*4+3] = fmaf(w.w, x0, d0[i4*4+3]); d1[i4*4+3] = fmaf(w.w, x1, d1[i4*4+3]);
      }
    }
    // store y1 + accumulate stats1
    float* yr0 = y1 + (size_t)(gcol + col0)*64 + ob;
    *(float4*)(yr0)     = make_float4(d0[0], d0[1], d0[2], d0[3]);
    *(float4*)(yr0 + 4) = make_float4(d0[4], d0[5], d0[6], d0[7]);
    float* yr1 = y1 + (size_t)(gcol + col0 + 1)*64 + ob;
    *(float4*)(yr1)     = make_float4(d1[0], d1[1], d1[2], d1[3]);
    *(float4*)(yr1 + 4) = make_float4(d1[4], d1[5], d1[6], d1[7]);
    #pragma unroll
    for (int i = 0; i < 8; ++i) {
      ts[i] += d0[i] + d1[i];
      tq[i] += d0[i]*d0[i] + d1[i]*d1[i];
    }
  }
  // butterfly within 32-lane halves (channels owned per half-wave)
  #pragma unroll
  for (int i = 0; i < 8; ++i) {
    float s = ts[i], q = tq[i];
    #pragma unroll
    for (int off = 1; off < 32; off <<= 1) {
      s += __shfl_xor(s, off, 64);
      q += __shfl_xor(q, off, 64);
    }
    if ((lane & 31) == 0) { atomicAdd(&stats1[ob+i], s); atomicAdd(&stats1[128+ob+i], q); }
  }
}

// ---------------- BN finalize ----------------
__global__ void k_fin(const float* __restrict__ stats, const float* __restrict__ g,
                      const float* __restrict__ be, float* __restrict__ aff, int C)
{
  int o = threadIdx.x;
  if (o < C) {
    float N = (float)NCOL;
    float mu = stats[o] / N;
    float var = stats[128+o]/N - mu*mu;
    float r = 1.0f / sqrtf(var + EPS_);
    float s = g[o]*r;
    aff[o] = s;
    aff[128+o] = fmaf(-mu, s, be[o]);
  }
}

// ========== shared stage for conv2 kernels: bn1(y1) -> XT[64][66] ==========
__device__ __forceinline__ void stage_bn1(const float* __restrict__ y1,
                                          const float* __restrict__ aff1,
                                          float* __restrict__ XT, int gcol, int tid)
{
  int scol = tid & 63, q = tid >> 6;
  const float4* yp = (const float4*)(y1 + (size_t)(gcol + scol)*64 + q*16);
  #pragma unroll
  for (int j4 = 0; j4 < 4; ++j4) {
    float4 v = yp[j4];
    int c = q*16 + j4*4;
    XT[(c+0)*66 + scol] = fmaxf(fmaf(v.x, aff1[c+0], aff1[128+c+0]), 0.f);
    XT[(c+1)*66 + scol] = fmaxf(fmaf(v.y, aff1[c+1], aff1[128+c+1]), 0.f);
    XT[(c+2)*66 + scol] = fmaxf(fmaf(v.z, aff1[c+2], aff1[128+c+2]), 0.f);
    XT[(c+3)*66 + scol] = fmaxf(fmaf(v.w, aff1[c+3], aff1[128+c+3]), 0.f);
  }
}

// ========== k_g2s: bn1 -> conv2 GEMM -> stats2 (no store). 8 iters x 64 cols ==========
__global__ __launch_bounds__(256) void k_g2s(
    const float* __restrict__ y1, const float* __restrict__ aff1,
    const float* __restrict__ Wt2, const float* __restrict__ b2,
    float* __restrict__ stats2)
{
  __shared__ float XT[64*66];
  __shared__ float W2L[64*128];
  const int tid = threadIdx.x, lane = tid & 63;
  for (int i = tid; i < 64*128; i += 256) W2L[i] = Wt2[i];
  const float4* W2L4 = (const float4*)W2L;

  const int col0 = 2*(lane & 31);                      // 64 cols
  const int ob   = (tid >> 6)*32 + (lane >> 5)*16;     // 8 groups x 16 = 128 outs
  float ts[16], tq[16];
  #pragma unroll
  for (int i = 0; i < 16; ++i) { ts[i] = 0.f; tq[i] = 0.f; }

  for (int it = 0; it < 8; ++it) {
    int gcol = blockIdx.x*512 + it*64;
    __syncthreads();
    stage_bn1(y1, aff1, XT, gcol, tid);
    __syncthreads();
    float acc0[16], acc1[16];
    #pragma unroll
    for (int i = 0; i < 16; ++i) { acc0[i] = b2[ob+i]; acc1[i] = acc0[i]; }
    for (int c = 0; c < 64; ++c) {
      float x0 = XT[c*66 + col0];
      float x1 = XT[c*66 + col0 + 1];
      #pragma unroll
      for (int i4 = 0; i4 < 4; ++i4) {
        float4 w = W2L4[c*32 + (ob>>2) + i4];
        acc0[i4*4+0] = fmaf(w.x, x0, acc0[i4*4+0]); acc1[i4*4+0] = fmaf(w.x, x1, acc1[i4*4+0]);
        acc0[i4*4+1] = fmaf(w.y, x0, acc0[i4*4+1]); acc1[i4*4+1] = fmaf(w.y, x1, acc1[i4*4+1]);
        acc0[i4*4+2] = fmaf(w.z, x0, acc0[i4*4+2]); acc1[i4*4+2] = fmaf(w.z, x1, acc1[i4*4+2]);
        acc0[i4*4+3] = fmaf(w.w, x0, acc0[i4*4+3]); acc1[i4*4+3] = fmaf(w.w, x1, acc1[i4*4+3]);
      }
    }
    #pragma unroll
    for (int i = 0; i < 16; ++i) {
      ts[i] += acc0[i] + acc1[i];
      tq[i] += acc0[i]*acc0[i] + acc1[i]*acc1[i];
    }
  }
  #pragma unroll
  for (int i = 0; i < 16; ++i) {
    float s = ts[i], q = tq[i];
    #pragma unroll
    for (int off = 1; off < 32; off <<= 1) {
      s += __shfl_xor(s, off, 64);
      q += __shfl_xor(q, off, 64);
    }
    if ((lane & 31) == 0) { atomicAdd(&stats2[ob+i], s); atomicAdd(&stats2[128+ob+i], q); }
  }
}

// ========== k_g2m: bn1 -> conv2 GEMM -> bn2/relu -> max_k -> out. 8 iters x 64 cols ==========
__global__ __launch_bounds__(256) void k_g2m(
    const float* __restrict__ y1, const float* __restrict__ aff1,
    const float* __restrict__ Wt2, const float* __restrict__ b2,
    const float* __restrict__ aff2, float* __restrict__ out)
{
  __shared__ float XT[64*66];
  __shared__ float W2L[64*128];
  const int tid = threadIdx.x, lane = tid & 63;
  for (int i = tid; i < 64*128; i += 256) W2L[i] = Wt2[i];
  const float4* W2L4 = (const float4*)W2L;

  const int col0 = 2*(lane & 31);
  const int ob   = (tid >> 6)*32 + (lane >> 5)*16;

  for (int it = 0; it < 8; ++it) {
    int gcol = blockIdx.x*512 + it*64;
    __syncthreads();
    stage_bn1(y1, aff1, XT, gcol, tid);
    __syncthreads();
    float acc0[16], acc1[16];
    #pragma unroll
    for (int i = 0; i < 16; ++i) { acc0[i] = b2[ob+i]; acc1[i] = acc0[i]; }
    for (int c = 0; c < 64; ++c) {
      float x0 = XT[c*66 + col0];
      float x1 = XT[c*66 + col0 + 1];
      #pragma unroll
      for (int i4 = 0; i4 < 4; ++i4) {
        float4 w = W2L4[c*32 + (ob>>2) + i4];
        acc0[i4*4+0] = fmaf(w.x, x0, acc0[i4*4+0]); acc1[i4*4+0] = fmaf(w.x, x1, acc1[i4*4+0]);
        acc0[i4*4+1] = fmaf(w.y, x0, acc0[i4*4+1]); acc1[i4*4+1] = fmaf(w.y, x1, acc1[i4*4+1]);
        acc0[i4*4+2] = fmaf(w.z, x0, acc0[i4*4+2]); acc1[i4*4+2] = fmaf(w.z, x1, acc1[i4*4+2]);
        acc0[i4*4+3] = fmaf(w.w, x0, acc0[i4*4+3]); acc1[i4*4+3] = fmaf(w.w, x1, acc1[i4*4+3]);
      }
    }
    // bn2 + relu + max over the 2 cols, then over 16-lane groups (one node each)
    float v[16];
    #pragma unroll
    for (int i = 0; i < 16; ++i) {
      int o = ob + i;
      float r0 = fmaxf(fmaf(acc0[i], aff2[o], aff2[128+o]), 0.f);
      float r1 = fmaxf(fmaf(acc1[i], aff2[o], aff2[128+o]), 0.f);
      v[i] = fmaxf(r0, r1);
      #pragma unroll
      for (int off = 1; off < 16; off <<= 1)
        v[i] = fmaxf(v[i], __shfl_xor(v[i], off, 64));
    }
    if ((lane & 15) == 0) {
      int node = (blockIdx.x*8 + it)*2 + ((lane >> 4) & 1);
      int b = node >> 11, m = node & 2047;
      float* op = out + ((size_t)b*128)*2048 + m;
      #pragma unroll
      for (int i = 0; i < 16; ++i)
        op[(size_t)(ob+i)*2048] = v[i];
    }
  }
}

extern "C" void kernel_launch(void* const* d_in, const int* in_sizes, int n_in,
                              void* d_out, int out_size, void* d_ws, size_t ws_size,
                              hipStream_t stream)
{
  const float* xyz   = (const float*)d_in[0];
  const float* feats = (const float*)d_in[1];
  const float* W0 = (const float*)d_in[2];
  const float* b0 = (const float*)d_in[3];
  const float* g0 = (const float*)d_in[4];
  const float* be0= (const float*)d_in[5];
  const float* W1 = (const float*)d_in[6];
  const float* b1 = (const float*)d_in[7];
  const float* g1 = (const float*)d_in[8];
  const float* be1= (const float*)d_in[9];
  const float* W2 = (const float*)d_in[10];
  const float* b2 = (const float*)d_in[11];
  const float* g2 = (const float*)d_in[12];
  const float* be2= (const float*)d_in[13];

  char* ws = (char*)d_ws;
  float* sx    = (float*)(ws + OFF_SX);
  int*   knn   = (int*  )(ws + OFF_KNN);
  float* ft    = (float*)(ws + OFF_FT);
  float* stats = (float*)(ws + OFF_ST);
  float* aff   = (float*)(ws + OFF_AF);
  float* Wt0   = (float*)(ws + OFF_W0);
  float* Wt1   = (float*)(ws + OFF_W1);
  float* Wt2   = (float*)(ws + OFF_W2);
  float* y1    = (float*)(ws + OFF_Y1);

  float* centers_out = (float*)d_out;              // 8*2048*3
  float* feat_out    = (float*)d_out + NNODE*3;    // 8*128*2048

  k_prep<<<256, 256, 0, stream>>>(xyz, W0, W1, W2, sx, Wt0, Wt1, Wt2, stats, centers_out);
  k_ft  <<<1024, 256, 0, stream>>>(feats, ft);
  k_knn <<<NNODE/4, 256, 0, stream>>>(xyz, sx, knn);
  k_g0  <<<1024, 256, 0, stream>>>(xyz, ft, knn, Wt0, b0, stats + 0);
  k_fin <<<1, 128, 0, stream>>>(stats + 0,   g0, be0, aff + 0,   64);
  k_g01 <<<1024, 256, 0, stream>>>(xyz, ft, knn, Wt0, b0, aff + 0, Wt1, b1, y1, stats + 256);
  k_fin <<<1, 128, 0, stream>>>(stats + 256, g1, be1, aff + 256, 64);
  k_g2s <<<1024, 256, 0, stream>>>(y1, aff + 256, Wt2, b2, stats + 512);
  k_fin <<<1, 128, 0, stream>>>(stats + 512, g2, be2, aff + 512, 128);
  k_g2m <<<1024, 256, 0, stream>>>(y1, aff + 256, Wt2, b2, aff + 512, feat_out);
}

// Round 9
// 2141.306 us; speedup vs baseline: 10.2401x; 1.3532x over previous
//
#include <hip/hip_runtime.h>
#include <math.h>

#define B_    8
#define P_    8192
#define M_    2048
#define NNODE 16384      // B_*M_
#define NCOL  524288     // NNODE*32
#define EPS_  1e-5f

// ---- ws layout (bytes) ---- (proven ≤ budget since r5)
#define OFF_SX   0ull                        // 65536 f32 = 262144
#define OFF_KNN  (OFF_SX + 262144ull)        // 524288 i32 = 2097152
#define OFF_FT   (OFF_KNN + 2097152ull)      // 8*8192*64 f32 = 16777216
#define OFF_ST   (OFF_FT + 16777216ull)      // 768 f32 (pad 4096)
#define OFF_AF   (OFF_ST + 4096ull)          // 768 f32 (pad 4096)
#define OFF_W0   (OFF_AF + 4096ull)          // 67*64 f32 = 17152
#define OFF_W1   (OFF_W0 + 17152ull)         // 64*64 f32 = 16384
#define OFF_W2   (OFF_W1 + 16384ull)         // 64*128 f32 = 32768
#define OFF_Y1   (OFF_W2 + 32768ull)         // 524288*64 f32 = 134217728
// total ~153 MB

// ---------------- prep ----------------
__global__ __launch_bounds__(256) void k_prep(
    const float* __restrict__ xyz, const float* __restrict__ W0,
    const float* __restrict__ W1, const float* __restrict__ W2,
    float* __restrict__ sx, float* __restrict__ Wt0, float* __restrict__ Wt1,
    float* __restrict__ Wt2, float* __restrict__ stats, float* __restrict__ centers_out)
{
  int idx = blockIdx.x*256 + threadIdx.x;
  if (idx < B_*P_) {
    const float* p3 = xyz + (size_t)idx*3;
    float x = p3[0], y = p3[1], z = p3[2];
    sx[idx] = __fadd_rn(__fadd_rn(__fmul_rn(x,x), __fmul_rn(y,y)), __fmul_rn(z,z));
  }
  if (idx < NNODE*3) {
    int m2 = idx/3, comp = idx - m2*3;
    int b = m2 >> 11, m = m2 & 2047;
    int cp = (m * 8191) / 2047;   // exact floor == int32(linspace), verified
    centers_out[idx] = xyz[((size_t)(b*P_ + cp))*3 + comp];
  }
  if (idx < 67*64) { int c = idx >> 6, o = idx & 63;  Wt0[idx] = W0[o*67 + c]; }
  if (idx < 64*64) { int c = idx >> 6, o = idx & 63;  Wt1[idx] = W1[o*64 + c]; }
  if (idx < 64*128){ int c = idx >> 7, o = idx & 127; Wt2[idx] = W2[o*64 + c]; }
  if (idx < 768)   stats[idx] = 0.f;
}

// ---------------- feats (b,c,p) -> ft (b,p,c) ----------------
__global__ __launch_bounds__(256) void k_ft(const float* __restrict__ feats, float* __restrict__ ft)
{
  int blk = blockIdx.x;            // 8*128
  int b = blk >> 7; int pt = (blk & 127) * 64;
  __shared__ float tile[64][65];
  const float* fb = feats + (size_t)b*64*P_;
  int tid = threadIdx.x;
  #pragma unroll
  for (int i = 0; i < 16; ++i) {
    int idx = i*256 + tid; int c = idx >> 6, p = idx & 63;
    tile[c][p] = fb[(size_t)c*P_ + pt + p];
  }
  __syncthreads();
  float* fo = ft + ((size_t)b*P_ + pt)*64;
  #pragma unroll
  for (int i = 0; i < 16; ++i) {
    int idx = i*256 + tid; int p = idx >> 6, c = idx & 63;
    fo[(size_t)p*64 + c] = tile[c][p];
  }
}

// ---------------- KNN v2: 1 center/block, wave-local tournament + 4-way merge ----
// Distance arithmetic VERBATIM from verified r5 kernel (DO NOT TOUCH).
// Selection set/order identical: ascending (fl32 d2, index) — u64 packing
// (sortable(f32) << 13 | p) preserves the exact float total order; p unique
// => u64 '<' == verified lexicographic comparator. -0.0 cannot occur (a-a=+0).
__global__ __launch_bounds__(256) void k_knn(const float* __restrict__ xyz,
                                             const float* __restrict__ sx,
                                             int* __restrict__ knn)
{
  __shared__ unsigned long long candP[128];   // 4 waves x 32 sorted candidates
  const int tid = threadIdx.x;
  const int lane = tid & 63, w = tid >> 6;
  const int cid = blockIdx.x;
  const int b = cid >> 11, m = cid & 2047;
  const int cp = (m * 8191) / 2047;
  const float* xb  = xyz + (size_t)b * P_ * 3;
  const float* sxb = sx + b * P_;
  const float cx = xb[cp*3+0], cy = xb[cp*3+1], cz = xb[cp*3+2];
  const float sc = sxb[cp];

  unsigned long long ks[32];
  #pragma unroll
  for (int i = 0; i < 32; ++i) {
    int p = w*2048 + i*64 + lane;
    float px = xb[p*3+0], py = xb[p*3+1], pz = xb[p*3+2];
    float dot = fmaf(cz, pz, fmaf(cy, py, __fmul_rn(cx, px)));
    float fk  = __fsub_rn(__fadd_rn(sc, sxb[p]), __fmul_rn(2.0f, dot));
    unsigned ub = __float_as_uint(fk);
    unsigned su = (ub & 0x80000000u) ? ~ub : (ub | 0x80000000u);
    ks[i] = ((unsigned long long)su << 13) | (unsigned)p;
  }
  // local best
  unsigned long long bv = ~0ull;
  #pragma unroll
  for (int i = 0; i < 32; ++i)
    if (ks[i] < bv) bv = ks[i];
  // 32 rounds, wave-internal (no barriers)
  unsigned rem = 0u;
  for (int r = 0; r < 32; ++r) {
    unsigned long long mn = bv;
    #pragma unroll
    for (int off = 1; off < 64; off <<= 1) {
      unsigned long long o = __shfl_xor(mn, off, 64);
      if (o < mn) mn = o;
    }
    if (lane == 0) candP[w*32 + r] = mn;
    if ((int)(mn & 63) == lane) {          // owner: remove + rescan
      rem |= 1u << (int)((mn >> 6) & 31);
      bv = ~0ull;
      #pragma unroll
      for (int i = 0; i < 32; ++i)
        if (!(rem & (1u<<i)) && ks[i] < bv) bv = ks[i];
    }
  }
  __syncthreads();
  // merge 4 sorted lists of 32 -> first 32 (lane 0 serial; values unique)
  if (tid == 0) {
    int h0=0,h1=0,h2=0,h3=0;
    unsigned long long v0=candP[0], v1=candP[32], v2=candP[64], v3=candP[96];
    int* kout = knn + cid*32;
    for (int r = 0; r < 32; ++r) {
      unsigned long long m01 = v0 < v1 ? v0 : v1;
      unsigned long long m23 = v2 < v3 ? v2 : v3;
      unsigned long long mn  = m01 < m23 ? m01 : m23;
      kout[r] = (int)(mn & 8191u);
      if      (mn == v0) { ++h0; v0 = (h0<32) ? candP[h0]    : ~0ull; }
      else if (mn == v1) { ++h1; v1 = (h1<32) ? candP[32+h1] : ~0ull; }
      else if (mn == v2) { ++h2; v2 = (h2<32) ? candP[64+h2] : ~0ull; }
      else               { ++h3; v3 = (h3<32) ? candP[96+h3] : ~0ull; }
    }
  }
}

// ========== k_g0: conv0 GEMM + stats0 (no store). 4 iters x 128 cols ==========
__global__ __launch_bounds__(256) void k_g0(
    const float* __restrict__ xyz, const float* __restrict__ ft,
    const int* __restrict__ knn, const float* __restrict__ Wt0,
    const float* __restrict__ b0, float* __restrict__ stats0)
{
  __shared__ float X0T[67*130];          // [c][col], stride 130
  __shared__ float W0L[67*64];           // [c][o]
  const int tid = threadIdx.x, lane = tid & 63;
  for (int i = tid; i < 67*64; i += 256) W0L[i] = Wt0[i];
  const float4* W0L4 = (const float4*)W0L;

  const int col0 = 2*(lane & 31) + 64*(lane >> 5);  // 128 cols
  const int ob   = (tid >> 6) * 16;                  // 4 waves x 16 outs
  float ts[16], tq[16];
  #pragma unroll
  for (int i = 0; i < 16; ++i) { ts[i] = 0.f; tq[i] = 0.f; }

  for (int it = 0; it < 4; ++it) {
    int gcol = blockIdx.x*512 + it*128;
    int b = gcol >> 16;
    __syncthreads();                      // protect X0T from prev iter readers
    {   // stage: col = tid&127, half = tid>>7
      int scol = tid & 127, half = tid >> 7;
      int p = knn[gcol + scol];
      if (half == 0) {
        const float* xp = xyz + ((size_t)(b*P_ + p))*3;
        X0T[0*130 + scol] = xp[0];
        X0T[1*130 + scol] = xp[1];
        X0T[2*130 + scol] = xp[2];
      }
      const float4* fp4 = (const float4*)(ft + ((size_t)(b*P_ + p))*64 + half*32);
      #pragma unroll
      for (int j4 = 0; j4 < 8; ++j4) {
        float4 v = fp4[j4];
        int r = 3 + half*32 + j4*4;
        X0T[(r+0)*130 + scol] = v.x;
        X0T[(r+1)*130 + scol] = v.y;
        X0T[(r+2)*130 + scol] = v.z;
        X0T[(r+3)*130 + scol] = v.w;
      }
    }
    __syncthreads();
    float acc0[16], acc1[16];
    #pragma unroll
    for (int i = 0; i < 16; ++i) { acc0[i] = b0[ob+i]; acc1[i] = acc0[i]; }
    for (int c = 0; c < 67; ++c) {
      float x0 = X0T[c*130 + col0];
      float x1 = X0T[c*130 + col0 + 1];
      #pragma unroll
      for (int i4 = 0; i4 < 4; ++i4) {
        float4 w = W0L4[c*16 + (ob>>2) + i4];
        acc0[i4*4+0] = fmaf(w.x, x0, acc0[i4*4+0]); acc1[i4*4+0] = fmaf(w.x, x1, acc1[i4*4+0]);
        acc0[i4*4+1] = fmaf(w.y, x0, acc0[i4*4+1]); acc1[i4*4+1] = fmaf(w.y, x1, acc1[i4*4+1]);
        acc0[i4*4+2] = fmaf(w.z, x0, acc0[i4*4+2]); acc1[i4*4+2] = fmaf(w.z, x1, acc1[i4*4+2]);
        acc0[i4*4+3] = fmaf(w.w, x0, acc0[i4*4+3]); acc1[i4*4+3] = fmaf(w.w, x1, acc1[i4*4+3]);
      }
    }
    #pragma unroll
    for (int i = 0; i < 16; ++i) {
      ts[i] += acc0[i] + acc1[i];
      tq[i] += acc0[i]*acc0[i] + acc1[i]*acc1[i];
    }
  }
  // butterfly over full wave (all 64 lanes share ob)
  #pragma unroll
  for (int i = 0; i < 16; ++i) {
    float s = ts[i], q = tq[i];
    #pragma unroll
    for (int off = 1; off < 64; off <<= 1) {
      s += __shfl_xor(s, off, 64);
      q += __shfl_xor(q, off, 64);
    }
    if (lane == 0) { atomicAdd(&stats0[ob+i], s); atomicAdd(&stats0[128+ob+i], q); }
  }
}

// ========== k_g01: conv0 -> bn0/relu -> conv1 -> y1 + stats1. 8 iters x 64 cols ==========
__global__ __launch_bounds__(256) void k_g01(
    const float* __restrict__ xyz, const float* __restrict__ ft,
    const int* __restrict__ knn, const float* __restrict__ Wt0,
    const float* __restrict__ b0, const float* __restrict__ aff0,
    const float* __restrict__ Wt1, const float* __restrict__ b1,
    float* __restrict__ y1, float* __restrict__ stats1)
{
  __shared__ float S[67*66];             // X0T [67][66] then XT [64][66]
  __shared__ float W0L[67*64];
  __shared__ float W1L[64*64];
  const int tid = threadIdx.x, lane = tid & 63;
  for (int i = tid; i < 67*64; i += 256) W0L[i] = Wt0[i];
  for (int i = tid; i < 64*64; i += 256) W1L[i] = Wt1[i];
  const float4* W0L4 = (const float4*)W0L;
  const float4* W1L4 = (const float4*)W1L;

  const int col0 = 2*(lane & 31);        // 64 cols
  const int og   = tid >> 5;             // 8 out-groups x 8
  const int ob   = og * 8;
  float ts[8], tq[8];
  #pragma unroll
  for (int i = 0; i < 8; ++i) { ts[i] = 0.f; tq[i] = 0.f; }

  for (int it = 0; it < 8; ++it) {
    int gcol = blockIdx.x*512 + it*64;
    int b = gcol >> 16;
    __syncthreads();
    {   // stage gather: col = tid&63, q = tid>>6
      int scol = tid & 63, q = tid >> 6;
      int p = knn[gcol + scol];
      if (q == 0) {
        const float* xp = xyz + ((size_t)(b*P_ + p))*3;
        S[0*66 + scol] = xp[0];
        S[1*66 + scol] = xp[1];
        S[2*66 + scol] = xp[2];
      }
      const float4* fp4 = (const float4*)(ft + ((size_t)(b*P_ + p))*64 + q*16);
      #pragma unroll
      for (int j4 = 0; j4 < 4; ++j4) {
        float4 v = fp4[j4];
        int r = 3 + q*16 + j4*4;
        S[(r+0)*66 + scol] = v.x;
        S[(r+1)*66 + scol] = v.y;
        S[(r+2)*66 + scol] = v.z;
        S[(r+3)*66 + scol] = v.w;
      }
    }
    __syncthreads();
    // conv0 GEMM
    float acc0[8], acc1[8];
    #pragma unroll
    for (int i = 0; i < 8; ++i) { acc0[i] = b0[ob+i]; acc1[i] = acc0[i]; }
    for (int c = 0; c < 67; ++c) {
      float x0 = S[c*66 + col0];
      float x1 = S[c*66 + col0 + 1];
      #pragma unroll
      for (int i4 = 0; i4 < 2; ++i4) {
        float4 w = W0L4[c*16 + og*2 + i4];
        acc0[i4*4+0] = fmaf(w.x, x0, acc0[i4*4+0]); acc1[i4*4+0] = fmaf(w.x, x1, acc1[i4*4+0]);
        acc0[i4*4+1] = fmaf(w.y, x0, acc0[i4*4+1]); acc1[i4*4+1] = fmaf(w.y, x1, acc1[i4*4+1]);
        acc0[i4*4+2] = fmaf(w.z, x0, acc0[i4*4+2]); acc1[i4*4+2] = fmaf(w.z, x1, acc1[i4*4+2]);
        acc0[i4*4+3] = fmaf(w.w, x0, acc0[i4*4+3]); acc1[i4*4+3] = fmaf(w.w, x1, acc1[i4*4+3]);
      }
    }
    // bn0 + relu
    #pragma unroll
    for (int i = 0; i < 8; ++i) {
      int o = ob + i;
      acc0[i] = fmaxf(fmaf(acc0[i], aff0[o], aff0[128+o]), 0.f);
      acc1[i] = fmaxf(fmaf(acc1[i], aff0[o], aff0[128+o]), 0.f);
    }
    __syncthreads();                     // all X0T reads done before overwrite
    #pragma unroll
    for (int i = 0; i < 8; ++i) {
      S[(ob+i)*66 + col0]     = acc0[i];
      S[(ob+i)*66 + col0 + 1] = acc1[i];
    }
    __syncthreads();
    // conv1 GEMM
    float d0[8], d1[8];
    #pragma unroll
    for (int i = 0; i < 8; ++i) { d0[i] = b1[ob+i]; d1[i] = d0[i]; }
    for (int c = 0; c < 64; ++c) {
      float x0 = S[c*66 + col0];
      float x1 = S[c*66 + col0 + 1];
      #pragma unroll
      for (int i4 = 0; i4 < 2; ++i4) {
        float4 w = W1L4[c*16 + og*2 + i4];
        d0[i4*4+0] = fmaf(w.x, x0, d0[i4*4+0]); d1[i4*4+0] = fmaf(w.x, x1, d1[i4*4+0]);
        d0[i4*4+1] = fmaf(w.y, x0, d0[i4*4+1]); d1[i4*4+1] = fmaf(w.y, x1, d1[i4*4+1]);
        d0[i4*4+2] = fmaf(w.z, x0, d0[i4*4+2]); d1[i4*4+2] = fmaf(w.z, x1, d1[i4*4+2]);
        d0[i4*4+3] = fmaf(w.w, x0, d0[i4*4+3]); d1[i4*4+3] = fmaf(w.w, x1, d1[i4*4+3]);
      }
    }
    // store y1 + accumulate stats1
    float* yr0 = y1 + (size_t)(gcol + col0)*64 + ob;
    *(float4*)(yr0)     = make_float4(d0[0], d0[1], d0[2], d0[3]);
    *(float4*)(yr0 + 4) = make_float4(d0[4], d0[5], d0[6], d0[7]);
    float* yr1 = y1 + (size_t)(gcol + col0 + 1)*64 + ob;
    *(float4*)(yr1)     = make_float4(d1[0], d1[1], d1[2], d1[3]);
    *(float4*)(yr1 + 4) = make_float4(d1[4], d1[5], d1[6], d1[7]);
    #pragma unroll
    for (int i = 0; i < 8; ++i) {
      ts[i] += d0[i] + d1[i];
      tq[i] += d0[i]*d0[i] + d1[i]*d1[i];
    }
  }
  // butterfly within 32-lane halves (channels owned per half-wave)
  #pragma unroll
  for (int i = 0; i < 8; ++i) {
    float s = ts[i], q = tq[i];
    #pragma unroll
    for (int off = 1; off < 32; off <<= 1) {
      s += __shfl_xor(s, off, 64);
      q += __shfl_xor(q, off, 64);
    }
    if ((lane & 31) == 0) { atomicAdd(&stats1[ob+i], s); atomicAdd(&stats1[128+ob+i], q); }
  }
}

// ---------------- BN finalize ----------------
__global__ void k_fin(const float* __restrict__ stats, const float* __restrict__ g,
                      const float* __restrict__ be, float* __restrict__ aff, int C)
{
  int o = threadIdx.x;
  if (o < C) {
    float N = (float)NCOL;
    float mu = stats[o] / N;
    float var = stats[128+o]/N - mu*mu;
    float r = 1.0f / sqrtf(var + EPS_);
    float s = g[o]*r;
    aff[o] = s;
    aff[128+o] = fmaf(-mu, s, be[o]);
  }
}

// ========== shared stage for conv2 kernels: bn1(y1) -> XT[64][66] ==========
__device__ __forceinline__ void stage_bn1(const float* __restrict__ y1,
                                          const float* __restrict__ aff1,
                                          float* __restrict__ XT, int gcol, int tid)
{
  int scol = tid & 63, q = tid >> 6;
  const float4* yp = (const float4*)(y1 + (size_t)(gcol + scol)*64 + q*16);
  #pragma unroll
  for (int j4 = 0; j4 < 4; ++j4) {
    float4 v = yp[j4];
    int c = q*16 + j4*4;
    XT[(c+0)*66 + scol] = fmaxf(fmaf(v.x, aff1[c+0], aff1[128+c+0]), 0.f);
    XT[(c+1)*66 + scol] = fmaxf(fmaf(v.y, aff1[c+1], aff1[128+c+1]), 0.f);
    XT[(c+2)*66 + scol] = fmaxf(fmaf(v.z, aff1[c+2], aff1[128+c+2]), 0.f);
    XT[(c+3)*66 + scol] = fmaxf(fmaf(v.w, aff1[c+3], aff1[128+c+3]), 0.f);
  }
}

// ========== k_g2s: bn1 -> conv2 GEMM -> stats2 (no store). 8 iters x 64 cols ==========
__global__ __launch_bounds__(256) void k_g2s(
    const float* __restrict__ y1, const float* __restrict__ aff1,
    const float* __restrict__ Wt2, const float* __restrict__ b2,
    float* __restrict__ stats2)
{
  __shared__ float XT[64*66];
  __shared__ float W2L[64*128];
  const int tid = threadIdx.x, lane = tid & 63;
  for (int i = tid; i < 64*128; i += 256) W2L[i] = Wt2[i];
  const float4* W2L4 = (const float4*)W2L;

  const int col0 = 2*(lane & 31);                      // 64 cols
  const int ob   = (tid >> 6)*32 + (lane >> 5)*16;     // 8 groups x 16 = 128 outs
  float ts[16], tq[16];
  #pragma unroll
  for (int i = 0; i < 16; ++i) { ts[i] = 0.f; tq[i] = 0.f; }

  for (int it = 0; it < 8; ++it) {
    int gcol = blockIdx.x*512 + it*64;
    __syncthreads();
    stage_bn1(y1, aff1, XT, gcol, tid);
    __syncthreads();
    float acc0[16], acc1[16];
    #pragma unroll
    for (int i = 0; i < 16; ++i) { acc0[i] = b2[ob+i]; acc1[i] = acc0[i]; }
    for (int c = 0; c < 64; ++c) {
      float x0 = XT[c*66 + col0];
      float x1 = XT[c*66 + col0 + 1];
      #pragma unroll
      for (int i4 = 0; i4 < 4; ++i4) {
        float4 w = W2L4[c*32 + (ob>>2) + i4];
        acc0[i4*4+0] = fmaf(w.x, x0, acc0[i4*4+0]); acc1[i4*4+0] = fmaf(w.x, x1, acc1[i4*4+0]);
        acc0[i4*4+1] = fmaf(w.y, x0, acc0[i4*4+1]); acc1[i4*4+1] = fmaf(w.y, x1, acc1[i4*4+1]);
        acc0[i4*4+2] = fmaf(w.z, x0, acc0[i4*4+2]); acc1[i4*4+2] = fmaf(w.z, x1, acc1[i4*4+2]);
        acc0[i4*4+3] = fmaf(w.w, x0, acc0[i4*4+3]); acc1[i4*4+3] = fmaf(w.w, x1, acc1[i4*4+3]);
      }
    }
    #pragma unroll
    for (int i = 0; i < 16; ++i) {
      ts[i] += acc0[i] + acc1[i];
      tq[i] += acc0[i]*acc0[i] + acc1[i]*acc1[i];
    }
  }
  #pragma unroll
  for (int i = 0; i < 16; ++i) {
    float s = ts[i], q = tq[i];
    #pragma unroll
    for (int off = 1; off < 32; off <<= 1) {
      s += __shfl_xor(s, off, 64);
      q += __shfl_xor(q, off, 64);
    }
    if ((lane & 31) == 0) { atomicAdd(&stats2[ob+i], s); atomicAdd(&stats2[128+ob+i], q); }
  }
}

// ========== k_g2m: bn1 -> conv2 GEMM -> bn2/relu -> max_k -> out. 8 iters x 64 cols ==========
__global__ __launch_bounds__(256) void k_g2m(
    const float* __restrict__ y1, const float* __restrict__ aff1,
    const float* __restrict__ Wt2, const float* __restrict__ b2,
    const float* __restrict__ aff2, float* __restrict__ out)
{
  __shared__ float XT[64*66];
  __shared__ float W2L[64*128];
  const int tid = threadIdx.x, lane = tid & 63;
  for (int i = tid; i < 64*128; i += 256) W2L[i] = Wt2[i];
  const float4* W2L4 = (const float4*)W2L;

  const int col0 = 2*(lane & 31);
  const int ob   = (tid >> 6)*32 + (lane >> 5)*16;

  for (int it = 0; it < 8; ++it) {
    int gcol = blockIdx.x*512 + it*64;
    __syncthreads();
    stage_bn1(y1, aff1, XT, gcol, tid);
    __syncthreads();
    float acc0[16], acc1[16];
    #pragma unroll
    for (int i = 0; i < 16; ++i) { acc0[i] = b2[ob+i]; acc1[i] = acc0[i]; }
    for (int c = 0; c < 64; ++c) {
      float x0 = XT[c*66 + col0];
      float x1 = XT[c*66 + col0 + 1];
      #pragma unroll
      for (int i4 = 0; i4 < 4; ++i4) {
        float4 w = W2L4[c*32 + (ob>>2) + i4];
        acc0[i4*4+0] = fmaf(w.x, x0, acc0[i4*4+0]); acc1[i4*4+0] = fmaf(w.x, x1, acc1[i4*4+0]);
        acc0[i4*4+1] = fmaf(w.y, x0, acc0[i4*4+1]); acc1[i4*4+1] = fmaf(w.y, x1, acc1[i4*4+1]);
        acc0[i4*4+2] = fmaf(w.z, x0, acc0[i4*4+2]); acc1[i4*4+2] = fmaf(w.z, x1, acc1[i4*4+2]);
        acc0[i4*4+3] = fmaf(w.w, x0, acc0[i4*4+3]); acc1[i4*4+3] = fmaf(w.w, x1, acc1[i4*4+3]);
      }
    }
    // bn2 + relu + max over the 2 cols, then over 16-lane groups (one node each)
    float v[16];
    #pragma unroll
    for (int i = 0; i < 16; ++i) {
      int o = ob + i;
      float r0 = fmaxf(fmaf(acc0[i], aff2[o], aff2[128+o]), 0.f);
      float r1 = fmaxf(fmaf(acc1[i], aff2[o], aff2[128+o]), 0.f);
      v[i] = fmaxf(r0, r1);
      #pragma unroll
      for (int off = 1; off < 16; off <<= 1)
        v[i] = fmaxf(v[i], __shfl_xor(v[i], off, 64));
    }
    if ((lane & 15) == 0) {
      int node = (blockIdx.x*8 + it)*2 + ((lane >> 4) & 1);
      int b = node >> 11, m = node & 2047;
      float* op = out + ((size_t)b*128)*2048 + m;
      #pragma unroll
      for (int i = 0; i < 16; ++i)
        op[(size_t)(ob+i)*2048] = v[i];
    }
  }
}

extern "C" void kernel_launch(void* const* d_in, const int* in_sizes, int n_in,
                              void* d_out, int out_size, void* d_ws, size_t ws_size,
                              hipStream_t stream)
{
  const float* xyz   = (const float*)d_in[0];
  const float* feats = (const float*)d_in[1];
  const float* W0 = (const float*)d_in[2];
  const float* b0 = (const float*)d_in[3];
  const float* g0 = (const float*)d_in[4];
  const float* be0= (const float*)d_in[5];
  const float* W1 = (const float*)d_in[6];
  const float* b1 = (const float*)d_in[7];
  const float* g1 = (const float*)d_in[8];
  const float* be1= (const float*)d_in[9];
  const float* W2 = (const float*)d_in[10];
  const float* b2 = (const float*)d_in[11];
  const float* g2 = (const float*)d_in[12];
  const float* be2= (const float*)d_in[13];

  char* ws = (char*)d_ws;
  float* sx    = (float*)(ws + OFF_SX);
  int*   knn   = (int*  )(ws + OFF_KNN);
  float* ft    = (float*)(ws + OFF_FT);
  float* stats = (float*)(ws + OFF_ST);
  float* aff   = (float*)(ws + OFF_AF);
  float* Wt0   = (float*)(ws + OFF_W0);
  float* Wt1   = (float*)(ws + OFF_W1);
  float* Wt2   = (float*)(ws + OFF_W2);
  float* y1    = (float*)(ws + OFF_Y1);

  float* centers_out = (float*)d_out;              // 8*2048*3
  float* feat_out    = (float*)d_out + NNODE*3;    // 8*128*2048

  k_prep<<<256, 256, 0, stream>>>(xyz, W0, W1, W2, sx, Wt0, Wt1, Wt2, stats, centers_out);
  k_ft  <<<1024, 256, 0, stream>>>(feats, ft);
  k_knn <<<NNODE, 256, 0, stream>>>(xyz, sx, knn);
  k_g0  <<<1024, 256, 0, stream>>>(xyz, ft, knn, Wt0, b0, stats + 0);
  k_fin <<<1, 128, 0, stream>>>(stats + 0,   g0, be0, aff + 0,   64);
  k_g01 <<<1024, 256, 0, stream>>>(xyz, ft, knn, Wt0, b0, aff + 0, Wt1, b1, y1, stats + 256);
  k_fin <<<1, 128, 0, stream>>>(stats + 256, g1, be1, aff + 256, 64);
  k_g2s <<<1024, 256, 0, stream>>>(y1, aff + 256, Wt2, b2, stats + 512);
  k_fin <<<1, 128, 0, stream>>>(stats + 512, g2, be2, aff + 512, 128);
  k_g2m <<<1024, 256, 0, stream>>>(y1, aff + 256, Wt2, b2, aff + 512, feat_out);
}

// Round 10
// 1605.307 us; speedup vs baseline: 13.6592x; 1.3339x over previous
//
#include <hip/hip_runtime.h>
#include <math.h>

#define B_    8
#define P_    8192
#define M_    2048
#define NNODE 16384      // B_*M_
#define NCOL  524288     // NNODE*32
#define EPS_  1e-5f

// ---- ws layout (bytes) ---- (proven ≤ budget since r5)
#define OFF_SX   0ull                        // 65536 f32 = 262144
#define OFF_KNN  (OFF_SX + 262144ull)        // 524288 i32 = 2097152
#define OFF_FT   (OFF_KNN + 2097152ull)      // 8*8192*64 f32 = 16777216
#define OFF_ST   (OFF_FT + 16777216ull)      // 768 f32 (pad 4096)
#define OFF_AF   (OFF_ST + 4096ull)          // 768 f32 (pad 4096)
#define OFF_W0   (OFF_AF + 4096ull)          // 67*64 f32 = 17152
#define OFF_W1   (OFF_W0 + 17152ull)         // 64*64 f32 = 16384
#define OFF_W2   (OFF_W1 + 16384ull)         // 64*128 f32 = 32768
#define OFF_Y1   (OFF_W2 + 32768ull)         // 524288*64 f32 = 134217728
// total ~153 MB

// ---------------- prep ----------------
__global__ __launch_bounds__(256) void k_prep(
    const float* __restrict__ xyz, const float* __restrict__ W0,
    const float* __restrict__ W1, const float* __restrict__ W2,
    float* __restrict__ sx, float* __restrict__ Wt0, float* __restrict__ Wt1,
    float* __restrict__ Wt2, float* __restrict__ stats, float* __restrict__ centers_out)
{
  int idx = blockIdx.x*256 + threadIdx.x;
  if (idx < B_*P_) {
    const float* p3 = xyz + (size_t)idx*3;
    float x = p3[0], y = p3[1], z = p3[2];
    sx[idx] = __fadd_rn(__fadd_rn(__fmul_rn(x,x), __fmul_rn(y,y)), __fmul_rn(z,z));
  }
  if (idx < NNODE*3) {
    int m2 = idx/3, comp = idx - m2*3;
    int b = m2 >> 11, m = m2 & 2047;
    int cp = (m * 8191) / 2047;   // exact floor == int32(linspace), verified
    centers_out[idx] = xyz[((size_t)(b*P_ + cp))*3 + comp];
  }
  if (idx < 67*64) { int c = idx >> 6, o = idx & 63;  Wt0[idx] = W0[o*67 + c]; }
  if (idx < 64*64) { int c = idx >> 6, o = idx & 63;  Wt1[idx] = W1[o*64 + c]; }
  if (idx < 64*128){ int c = idx >> 7, o = idx & 127; Wt2[idx] = W2[o*64 + c]; }
  if (idx < 768)   stats[idx] = 0.f;
}

// ---------------- feats (b,c,p) -> ft (b,p,c) ----------------
__global__ __launch_bounds__(256) void k_ft(const float* __restrict__ feats, float* __restrict__ ft)
{
  int blk = blockIdx.x;            // 8*128
  int b = blk >> 7; int pt = (blk & 127) * 64;
  __shared__ float tile[64][65];
  const float* fb = feats + (size_t)b*64*P_;
  int tid = threadIdx.x;
  #pragma unroll
  for (int i = 0; i < 16; ++i) {
    int idx = i*256 + tid; int c = idx >> 6, p = idx & 63;
    tile[c][p] = fb[(size_t)c*P_ + pt + p];
  }
  __syncthreads();
  float* fo = ft + ((size_t)b*P_ + pt)*64;
  #pragma unroll
  for (int i = 0; i < 16; ++i) {
    int idx = i*256 + tid; int p = idx >> 6, c = idx & 63;
    fo[(size_t)p*64 + c] = tile[c][p];
  }
}

// ---------------- KNN v3: 1 wave per center, top-4 lists, O(1) pop ----------------
// Distance arithmetic VERBATIM from verified r5 kernel. Key = (sortable(f32)<<13)|p
// preserves exact (fl32 d2, index) lexicographic order (verified in r9). Each lane
// keeps its 4 smallest keys sorted; wave butterfly extracts global min 32 times;
// owner pops O(1). Rare refill (lane owns >4 of top-32) recomputes keys > last
// extracted value (deterministic, bit-identical recompute).
__global__ __launch_bounds__(256) void k_knn(const float* __restrict__ xyz,
                                             const float* __restrict__ sx,
                                             int* __restrict__ knn)
{
  const int tid = threadIdx.x;
  const int lane = tid & 63, w = tid >> 6;
  const int cid = blockIdx.x*4 + w;
  const int b = cid >> 11, m = cid & 2047;
  const int cp = (m * 8191) / 2047;
  const float* xb  = xyz + (size_t)b * P_ * 3;
  const float* sxb = sx + b * P_;
  const float cx = xb[cp*3+0], cy = xb[cp*3+1], cz = xb[cp*3+2];
  const float sc = sxb[cp];
  const unsigned long long EMPTY = ~0ull;

  unsigned long long l0 = EMPTY, l1 = EMPTY, l2 = EMPTY, l3 = EMPTY;

  #pragma unroll 4
  for (int i = 0; i < 128; ++i) {
    int p = i*64 + lane;
    float px = xb[p*3+0], py = xb[p*3+1], pz = xb[p*3+2];
    float dot = fmaf(cz, pz, fmaf(cy, py, __fmul_rn(cx, px)));
    float fk  = __fsub_rn(__fadd_rn(sc, sxb[p]), __fmul_rn(2.0f, dot));
    unsigned ub = __float_as_uint(fk);
    unsigned su = ub ^ (0x80000000u | (unsigned)((int)ub >> 31));  // sortable f32
    unsigned long long k = ((unsigned long long)su << 13) | (unsigned)p;
    // sorted insert into (l0<=l1<=l2<=l3), drop max
    unsigned long long m3 = k < l3 ? k : l3;
    bool c2 = m3 < l2;
    unsigned long long n2 = c2 ? m3 : l2, n3 = c2 ? l2 : m3;
    bool c1 = n2 < l1;
    unsigned long long n1 = c1 ? n2 : l1; n2 = c1 ? l1 : n2;
    bool c0 = n1 < l0;
    unsigned long long nl0 = c0 ? n1 : l0; n1 = c0 ? l0 : n1;
    l0 = nl0; l1 = n1; l2 = n2; l3 = n3;
  }

  int* kout = knn + cid*32;
  for (int r = 0; r < 32; ++r) {
    unsigned long long mn = l0;
    #pragma unroll
    for (int off = 1; off < 64; off <<= 1) {
      unsigned long long o = __shfl_xor(mn, off, 64);
      if (o < mn) mn = o;
    }
    if (lane == 0) kout[r] = (int)(mn & 8191u);
    bool mine = ((int)(mn & 63u) == lane);
    if (mine) { l0 = l1; l1 = l2; l2 = l3; l3 = EMPTY; }
    if (mine && l0 == EMPTY) {
      // refill: 4 smallest keys strictly greater than mn (all unconsumed > mn)
      #pragma unroll 1
      for (int i = 0; i < 128; ++i) {
        int p = i*64 + lane;
        float px = xb[p*3+0], py = xb[p*3+1], pz = xb[p*3+2];
        float dot = fmaf(cz, pz, fmaf(cy, py, __fmul_rn(cx, px)));
        float fk  = __fsub_rn(__fadd_rn(sc, sxb[p]), __fmul_rn(2.0f, dot));
        unsigned ub = __float_as_uint(fk);
        unsigned su = ub ^ (0x80000000u | (unsigned)((int)ub >> 31));
        unsigned long long k = ((unsigned long long)su << 13) | (unsigned)p;
        k = (k > mn) ? k : EMPTY;
        unsigned long long m3 = k < l3 ? k : l3;
        bool c2 = m3 < l2;
        unsigned long long n2 = c2 ? m3 : l2, n3 = c2 ? l2 : m3;
        bool c1 = n2 < l1;
        unsigned long long n1 = c1 ? n2 : l1; n2 = c1 ? l1 : n2;
        bool c0 = n1 < l0;
        unsigned long long nl0 = c0 ? n1 : l0; n1 = c0 ? l0 : n1;
        l0 = nl0; l1 = n1; l2 = n2; l3 = n3;
      }
    }
  }
}

// ========== k_g0: conv0 GEMM + stats0 (no store). 4 iters x 128 cols ==========
__global__ __launch_bounds__(256) void k_g0(
    const float* __restrict__ xyz, const float* __restrict__ ft,
    const int* __restrict__ knn, const float* __restrict__ Wt0,
    const float* __restrict__ b0, float* __restrict__ stats0)
{
  __shared__ float X0T[67*130];          // [c][col], stride 130
  __shared__ float W0L[67*64];           // [c][o]
  const int tid = threadIdx.x, lane = tid & 63;
  for (int i = tid; i < 67*64; i += 256) W0L[i] = Wt0[i];
  const float4* W0L4 = (const float4*)W0L;

  const int col0 = 2*(lane & 31) + 64*(lane >> 5);  // 128 cols
  const int ob   = (tid >> 6) * 16;                  // 4 waves x 16 outs
  float ts[16], tq[16];
  #pragma unroll
  for (int i = 0; i < 16; ++i) { ts[i] = 0.f; tq[i] = 0.f; }

  for (int it = 0; it < 4; ++it) {
    int gcol = blockIdx.x*512 + it*128;
    int b = gcol >> 16;
    __syncthreads();                      // protect X0T from prev iter readers
    {   // stage: col = tid&127, half = tid>>7
      int scol = tid & 127, half = tid >> 7;
      int p = knn[gcol + scol];
      if (half == 0) {
        const float* xp = xyz + ((size_t)(b*P_ + p))*3;
        X0T[0*130 + scol] = xp[0];
        X0T[1*130 + scol] = xp[1];
        X0T[2*130 + scol] = xp[2];
      }
      const float4* fp4 = (const float4*)(ft + ((size_t)(b*P_ + p))*64 + half*32);
      #pragma unroll
      for (int j4 = 0; j4 < 8; ++j4) {
        float4 v = fp4[j4];
        int r = 3 + half*32 + j4*4;
        X0T[(r+0)*130 + scol] = v.x;
        X0T[(r+1)*130 + scol] = v.y;
        X0T[(r+2)*130 + scol] = v.z;
        X0T[(r+3)*130 + scol] = v.w;
      }
    }
    __syncthreads();
    float acc0[16], acc1[16];
    #pragma unroll
    for (int i = 0; i < 16; ++i) { acc0[i] = b0[ob+i]; acc1[i] = acc0[i]; }
    for (int c = 0; c < 67; ++c) {
      float x0 = X0T[c*130 + col0];
      float x1 = X0T[c*130 + col0 + 1];
      #pragma unroll
      for (int i4 = 0; i4 < 4; ++i4) {
        float4 w = W0L4[c*16 + (ob>>2) + i4];
        acc0[i4*4+0] = fmaf(w.x, x0, acc0[i4*4+0]); acc1[i4*4+0] = fmaf(w.x, x1, acc1[i4*4+0]);
        acc0[i4*4+1] = fmaf(w.y, x0, acc0[i4*4+1]); acc1[i4*4+1] = fmaf(w.y, x1, acc1[i4*4+1]);
        acc0[i4*4+2] = fmaf(w.z, x0, acc0[i4*4+2]); acc1[i4*4+2] = fmaf(w.z, x1, acc1[i4*4+2]);
        acc0[i4*4+3] = fmaf(w.w, x0, acc0[i4*4+3]); acc1[i4*4+3] = fmaf(w.w, x1, acc1[i4*4+3]);
      }
    }
    #pragma unroll
    for (int i = 0; i < 16; ++i) {
      ts[i] += acc0[i] + acc1[i];
      tq[i] += acc0[i]*acc0[i] + acc1[i]*acc1[i];
    }
  }
  // butterfly over full wave (all 64 lanes share ob)
  #pragma unroll
  for (int i = 0; i < 16; ++i) {
    float s = ts[i], q = tq[i];
    #pragma unroll
    for (int off = 1; off < 64; off <<= 1) {
      s += __shfl_xor(s, off, 64);
      q += __shfl_xor(q, off, 64);
    }
    if (lane == 0) { atomicAdd(&stats0[ob+i], s); atomicAdd(&stats0[128+ob+i], q); }
  }
}

// ========== k_g01: conv0 -> bn0/relu -> conv1 -> y1 + stats1. 8 iters x 64 cols ==========
__global__ __launch_bounds__(256) void k_g01(
    const float* __restrict__ xyz, const float* __restrict__ ft,
    const int* __restrict__ knn, const float* __restrict__ Wt0,
    const float* __restrict__ b0, const float* __restrict__ aff0,
    const float* __restrict__ Wt1, const float* __restrict__ b1,
    float* __restrict__ y1, float* __restrict__ stats1)
{
  __shared__ float S[67*66];             // X0T [67][66] then XT [64][66]
  __shared__ float W0L[67*64];
  __shared__ float W1L[64*64];
  const int tid = threadIdx.x, lane = tid & 63;
  for (int i = tid; i < 67*64; i += 256) W0L[i] = Wt0[i];
  for (int i = tid; i < 64*64; i += 256) W1L[i] = Wt1[i];
  const float4* W0L4 = (const float4*)W0L;
  const float4* W1L4 = (const float4*)W1L;

  const int col0 = 2*(lane & 31);        // 64 cols
  const int og   = tid >> 5;             // 8 out-groups x 8
  const int ob   = og * 8;
  float ts[8], tq[8];
  #pragma unroll
  for (int i = 0; i < 8; ++i) { ts[i] = 0.f; tq[i] = 0.f; }

  for (int it = 0; it < 8; ++it) {
    int gcol = blockIdx.x*512 + it*64;
    int b = gcol >> 16;
    __syncthreads();
    {   // stage gather: col = tid&63, q = tid>>6
      int scol = tid & 63, q = tid >> 6;
      int p = knn[gcol + scol];
      if (q == 0) {
        const float* xp = xyz + ((size_t)(b*P_ + p))*3;
        S[0*66 + scol] = xp[0];
        S[1*66 + scol] = xp[1];
        S[2*66 + scol] = xp[2];
      }
      const float4* fp4 = (const float4*)(ft + ((size_t)(b*P_ + p))*64 + q*16);
      #pragma unroll
      for (int j4 = 0; j4 < 4; ++j4) {
        float4 v = fp4[j4];
        int r = 3 + q*16 + j4*4;
        S[(r+0)*66 + scol] = v.x;
        S[(r+1)*66 + scol] = v.y;
        S[(r+2)*66 + scol] = v.z;
        S[(r+3)*66 + scol] = v.w;
      }
    }
    __syncthreads();
    // conv0 GEMM
    float acc0[8], acc1[8];
    #pragma unroll
    for (int i = 0; i < 8; ++i) { acc0[i] = b0[ob+i]; acc1[i] = acc0[i]; }
    for (int c = 0; c < 67; ++c) {
      float x0 = S[c*66 + col0];
      float x1 = S[c*66 + col0 + 1];
      #pragma unroll
      for (int i4 = 0; i4 < 2; ++i4) {
        float4 w = W0L4[c*16 + og*2 + i4];
        acc0[i4*4+0] = fmaf(w.x, x0, acc0[i4*4+0]); acc1[i4*4+0] = fmaf(w.x, x1, acc1[i4*4+0]);
        acc0[i4*4+1] = fmaf(w.y, x0, acc0[i4*4+1]); acc1[i4*4+1] = fmaf(w.y, x1, acc1[i4*4+1]);
        acc0[i4*4+2] = fmaf(w.z, x0, acc0[i4*4+2]); acc1[i4*4+2] = fmaf(w.z, x1, acc1[i4*4+2]);
        acc0[i4*4+3] = fmaf(w.w, x0, acc0[i4*4+3]); acc1[i4*4+3] = fmaf(w.w, x1, acc1[i4*4+3]);
      }
    }
    // bn0 + relu
    #pragma unroll
    for (int i = 0; i < 8; ++i) {
      int o = ob + i;
      acc0[i] = fmaxf(fmaf(acc0[i], aff0[o], aff0[128+o]), 0.f);
      acc1[i] = fmaxf(fmaf(acc1[i], aff0[o], aff0[128+o]), 0.f);
    }
    __syncthreads();                     // all X0T reads done before overwrite
    #pragma unroll
    for (int i = 0; i < 8; ++i) {
      S[(ob+i)*66 + col0]     = acc0[i];
      S[(ob+i)*66 + col0 + 1] = acc1[i];
    }
    __syncthreads();
    // conv1 GEMM
    float d0[8], d1[8];
    #pragma unroll
    for (int i = 0; i < 8; ++i) { d0[i] = b1[ob+i]; d1[i] = d0[i]; }
    for (int c = 0; c < 64; ++c) {
      float x0 = S[c*66 + col0];
      float x1 = S[c*66 + col0 + 1];
      #pragma unroll
      for (int i4 = 0; i4 < 2; ++i4) {
        float4 w = W1L4[c*16 + og*2 + i4];
        d0[i4*4+0] = fmaf(w.x, x0, d0[i4*4+0]); d1[i4*4+0] = fmaf(w.x, x1, d1[i4*4+0]);
        d0[i4*4+1] = fmaf(w.y, x0, d0[i4*4+1]); d1[i4*4+1] = fmaf(w.y, x1, d1[i4*4+1]);
        d0[i4*4+2] = fmaf(w.z, x0, d0[i4*4+2]); d1[i4*4+2] = fmaf(w.z, x1, d1[i4*4+2]);
        d0[i4*4+3] = fmaf(w.w, x0, d0[i4*4+3]); d1[i4*4+3] = fmaf(w.w, x1, d1[i4*4+3]);
      }
    }
    // store y1 + accumulate stats1
    float* yr0 = y1 + (size_t)(gcol + col0)*64 + ob;
    *(float4*)(yr0)     = make_float4(d0[0], d0[1], d0[2], d0[3]);
    *(float4*)(yr0 + 4) = make_float4(d0[4], d0[5], d0[6], d0[7]);
    float* yr1 = y1 + (size_t)(gcol + col0 + 1)*64 + ob;
    *(float4*)(yr1)     = make_float4(d1[0], d1[1], d1[2], d1[3]);
    *(float4*)(yr1 + 4) = make_float4(d1[4], d1[5], d1[6], d1[7]);
    #pragma unroll
    for (int i = 0; i < 8; ++i) {
      ts[i] += d0[i] + d1[i];
      tq[i] += d0[i]*d0[i] + d1[i]*d1[i];
    }
  }
  // butterfly within 32-lane halves (channels owned per half-wave)
  #pragma unroll
  for (int i = 0; i < 8; ++i) {
    float s = ts[i], q = tq[i];
    #pragma unroll
    for (int off = 1; off < 32; off <<= 1) {
      s += __shfl_xor(s, off, 64);
      q += __shfl_xor(q, off, 64);
    }
    if ((lane & 31) == 0) { atomicAdd(&stats1[ob+i], s); atomicAdd(&stats1[128+ob+i], q); }
  }
}

// ---------------- BN finalize ----------------
__global__ void k_fin(const float* __restrict__ stats, const float* __restrict__ g,
                      const float* __restrict__ be, float* __restrict__ aff, int C)
{
  int o = threadIdx.x;
  if (o < C) {
    float N = (float)NCOL;
    float mu = stats[o] / N;
    float var = stats[128+o]/N - mu*mu;
    float r = 1.0f / sqrtf(var + EPS_);
    float s = g[o]*r;
    aff[o] = s;
    aff[128+o] = fmaf(-mu, s, be[o]);
  }
}

// ========== shared stage for conv2 kernels: bn1(y1) -> XT[64][66] ==========
__device__ __forceinline__ void stage_bn1(const float* __restrict__ y1,
                                          const float* __restrict__ aff1,
                                          float* __restrict__ XT, int gcol, int tid)
{
  int scol = tid & 63, q = tid >> 6;
  const float4* yp = (const float4*)(y1 + (size_t)(gcol + scol)*64 + q*16);
  #pragma unroll
  for (int j4 = 0; j4 < 4; ++j4) {
    float4 v = yp[j4];
    int c = q*16 + j4*4;
    XT[(c+0)*66 + scol] = fmaxf(fmaf(v.x, aff1[c+0], aff1[128+c+0]), 0.f);
    XT[(c+1)*66 + scol] = fmaxf(fmaf(v.y, aff1[c+1], aff1[128+c+1]), 0.f);
    XT[(c+2)*66 + scol] = fmaxf(fmaf(v.z, aff1[c+2], aff1[128+c+2]), 0.f);
    XT[(c+3)*66 + scol] = fmaxf(fmaf(v.w, aff1[c+3], aff1[128+c+3]), 0.f);
  }
}

// ========== k_g2s: bn1 -> conv2 GEMM -> stats2 (no store). 8 iters x 64 cols ==========
__global__ __launch_bounds__(256) void k_g2s(
    const float* __restrict__ y1, const float* __restrict__ aff1,
    const float* __restrict__ Wt2, const float* __restrict__ b2,
    float* __restrict__ stats2)
{
  __shared__ float XT[64*66];
  __shared__ float W2L[64*128];
  const int tid = threadIdx.x, lane = tid & 63;
  for (int i = tid; i < 64*128; i += 256) W2L[i] = Wt2[i];
  const float4* W2L4 = (const float4*)W2L;

  const int col0 = 2*(lane & 31);                      // 64 cols
  const int ob   = (tid >> 6)*32 + (lane >> 5)*16;     // 8 groups x 16 = 128 outs
  float ts[16], tq[16];
  #pragma unroll
  for (int i = 0; i < 16; ++i) { ts[i] = 0.f; tq[i] = 0.f; }

  for (int it = 0; it < 8; ++it) {
    int gcol = blockIdx.x*512 + it*64;
    __syncthreads();
    stage_bn1(y1, aff1, XT, gcol, tid);
    __syncthreads();
    float acc0[16], acc1[16];
    #pragma unroll
    for (int i = 0; i < 16; ++i) { acc0[i] = b2[ob+i]; acc1[i] = acc0[i]; }
    for (int c = 0; c < 64; ++c) {
      float x0 = XT[c*66 + col0];
      float x1 = XT[c*66 + col0 + 1];
      #pragma unroll
      for (int i4 = 0; i4 < 4; ++i4) {
        float4 w = W2L4[c*32 + (ob>>2) + i4];
        acc0[i4*4+0] = fmaf(w.x, x0, acc0[i4*4+0]); acc1[i4*4+0] = fmaf(w.x, x1, acc1[i4*4+0]);
        acc0[i4*4+1] = fmaf(w.y, x0, acc0[i4*4+1]); acc1[i4*4+1] = fmaf(w.y, x1, acc1[i4*4+1]);
        acc0[i4*4+2] = fmaf(w.z, x0, acc0[i4*4+2]); acc1[i4*4+2] = fmaf(w.z, x1, acc1[i4*4+2]);
        acc0[i4*4+3] = fmaf(w.w, x0, acc0[i4*4+3]); acc1[i4*4+3] = fmaf(w.w, x1, acc1[i4*4+3]);
      }
    }
    #pragma unroll
    for (int i = 0; i < 16; ++i) {
      ts[i] += acc0[i] + acc1[i];
      tq[i] += acc0[i]*acc0[i] + acc1[i]*acc1[i];
    }
  }
  #pragma unroll
  for (int i = 0; i < 16; ++i) {
    float s = ts[i], q = tq[i];
    #pragma unroll
    for (int off = 1; off < 32; off <<= 1) {
      s += __shfl_xor(s, off, 64);
      q += __shfl_xor(q, off, 64);
    }
    if ((lane & 31) == 0) { atomicAdd(&stats2[ob+i], s); atomicAdd(&stats2[128+ob+i], q); }
  }
}

// ========== k_g2m: bn1 -> conv2 GEMM -> bn2/relu -> max_k -> out. 8 iters x 64 cols ==========
__global__ __launch_bounds__(256) void k_g2m(
    const float* __restrict__ y1, const float* __restrict__ aff1,
    const float* __restrict__ Wt2, const float* __restrict__ b2,
    const float* __restrict__ aff2, float* __restrict__ out)
{
  __shared__ float XT[64*66];
  __shared__ float W2L[64*128];
  const int tid = threadIdx.x, lane = tid & 63;
  for (int i = tid; i < 64*128; i += 256) W2L[i] = Wt2[i];
  const float4* W2L4 = (const float4*)W2L;

  const int col0 = 2*(lane & 31);
  const int ob   = (tid >> 6)*32 + (lane >> 5)*16;

  for (int it = 0; it < 8; ++it) {
    int gcol = blockIdx.x*512 + it*64;
    __syncthreads();
    stage_bn1(y1, aff1, XT, gcol, tid);
    __syncthreads();
    float acc0[16], acc1[16];
    #pragma unroll
    for (int i = 0; i < 16; ++i) { acc0[i] = b2[ob+i]; acc1[i] = acc0[i]; }
    for (int c = 0; c < 64; ++c) {
      float x0 = XT[c*66 + col0];
      float x1 = XT[c*66 + col0 + 1];
      #pragma unroll
      for (int i4 = 0; i4 < 4; ++i4) {
        float4 w = W2L4[c*32 + (ob>>2) + i4];
        acc0[i4*4+0] = fmaf(w.x, x0, acc0[i4*4+0]); acc1[i4*4+0] = fmaf(w.x, x1, acc1[i4*4+0]);
        acc0[i4*4+1] = fmaf(w.y, x0, acc0[i4*4+1]); acc1[i4*4+1] = fmaf(w.y, x1, acc1[i4*4+1]);
        acc0[i4*4+2] = fmaf(w.z, x0, acc0[i4*4+2]); acc1[i4*4+2] = fmaf(w.z, x1, acc1[i4*4+2]);
        acc0[i4*4+3] = fmaf(w.w, x0, acc0[i4*4+3]); acc1[i4*4+3] = fmaf(w.w, x1, acc1[i4*4+3]);
      }
    }
    // bn2 + relu + max over the 2 cols, then over 16-lane groups (one node each)
    float v[16];
    #pragma unroll
    for (int i = 0; i < 16; ++i) {
      int o = ob + i;
      float r0 = fmaxf(fmaf(acc0[i], aff2[o], aff2[128+o]), 0.f);
      float r1 = fmaxf(fmaf(acc1[i], aff2[o], aff2[128+o]), 0.f);
      v[i] = fmaxf(r0, r1);
      #pragma unroll
      for (int off = 1; off < 16; off <<= 1)
        v[i] = fmaxf(v[i], __shfl_xor(v[i], off, 64));
    }
    if ((lane & 15) == 0) {
      int node = (blockIdx.x*8 + it)*2 + ((lane >> 4) & 1);
      int b = node >> 11, m = node & 2047;
      float* op = out + ((size_t)b*128)*2048 + m;
      #pragma unroll
      for (int i = 0; i < 16; ++i)
        op[(size_t)(ob+i)*2048] = v[i];
    }
  }
}

extern "C" void kernel_launch(void* const* d_in, const int* in_sizes, int n_in,
                              void* d_out, int out_size, void* d_ws, size_t ws_size,
                              hipStream_t stream)
{
  const float* xyz   = (const float*)d_in[0];
  const float* feats = (const float*)d_in[1];
  const float* W0 = (const float*)d_in[2];
  const float* b0 = (const float*)d_in[3];
  const float* g0 = (const float*)d_in[4];
  const float* be0= (const float*)d_in[5];
  const float* W1 = (const float*)d_in[6];
  const float* b1 = (const float*)d_in[7];
  const float* g1 = (const float*)d_in[8];
  const float* be1= (const float*)d_in[9];
  const float* W2 = (const float*)d_in[10];
  const float* b2 = (const float*)d_in[11];
  const float* g2 = (const float*)d_in[12];
  const float* be2= (const float*)d_in[13];

  char* ws = (char*)d_ws;
  float* sx    = (float*)(ws + OFF_SX);
  int*   knn   = (int*  )(ws + OFF_KNN);
  float* ft    = (float*)(ws + OFF_FT);
  float* stats = (float*)(ws + OFF_ST);
  float* aff   = (float*)(ws + OFF_AF);
  float* Wt0   = (float*)(ws + OFF_W0);
  float* Wt1   = (float*)(ws + OFF_W1);
  float* Wt2   = (float*)(ws + OFF_W2);
  float* y1    = (float*)(ws + OFF_Y1);

  float* centers_out = (float*)d_out;              // 8*2048*3
  float* feat_out    = (float*)d_out + NNODE*3;    // 8*128*2048

  k_prep<<<256, 256, 0, stream>>>(xyz, W0, W1, W2, sx, Wt0, Wt1, Wt2, stats, centers_out);
  k_ft  <<<1024, 256, 0, stream>>>(feats, ft);
  k_knn <<<NNODE/4, 256, 0, stream>>>(xyz, sx, knn);
  k_g0  <<<1024, 256, 0, stream>>>(xyz, ft, knn, Wt0, b0, stats + 0);
  k_fin <<<1, 128, 0, stream>>>(stats + 0,   g0, be0, aff + 0,   64);
  k_g01 <<<1024, 256, 0, stream>>>(xyz, ft, knn, Wt0, b0, aff + 0, Wt1, b1, y1, stats + 256);
  k_fin <<<1, 128, 0, stream>>>(stats + 256, g1, be1, aff + 256, 64);
  k_g2s <<<1024, 256, 0, stream>>>(y1, aff + 256, Wt2, b2, stats + 512);
  k_fin <<<1, 128, 0, stream>>>(stats + 512, g2, be2, aff + 512, 128);
  k_g2m <<<1024, 256, 0, stream>>>(y1, aff + 256, Wt2, b2, aff + 512, feat_out);
}